// Round 17
// baseline (393.547 us; speedup 1.0000x reference)
//
#include <hip/hip_runtime.h>
#include <hip/hip_bf16.h>
#include <math.h>

#define NN 50000     // nodes
#define NE 400000    // edges
#define HH 4         // heads
#define CC 64        // per-head dim
#define HC 256       // H*C
#define GG 64        // graphs
#define NB 196       // scan blocks: ceil(NN/256)

typedef short v8s __attribute__((ext_vector_type(8)));
typedef float f32x4 __attribute__((ext_vector_type(4)));

static __device__ inline unsigned short f2bf(float v) {
  __hip_bfloat16 b = __float2bfloat16(v);
  return *reinterpret_cast<unsigned short*>(&b);
}
// packed bf16 pair -> f32 (bf16 value = bit pattern << 16)
static __device__ inline float bflo(unsigned u) { return __uint_as_float(u << 16); }
static __device__ inline float bfhi(unsigned u) { return __uint_as_float(u & 0xffff0000u); }

// ---------------- encoder: h0 = relu(x @ enc_w + enc_b) -> bf16 ----------------
__global__ __launch_bounds__(256) void encoder_kernel(
    const float* __restrict__ x, const float* __restrict__ w,
    const float* __restrict__ b, unsigned short* __restrict__ h0) {
  int idx = blockIdx.x * 256 + threadIdx.x;   // N*64 threads
  int node = idx >> 6, col = idx & 63;
  const float* xr = x + node * 8;
  float acc = b[col];
#pragma unroll
  for (int k = 0; k < 8; ++k) acc += xr[k] * w[k * 64 + col];
  h0[idx] = f2bf(fmaxf(acc, 0.f));
}

// ---- W prep: W[K,256] f32 -> Wt bf16 [256][K] (k-contiguous rows) ----
__global__ __launch_bounds__(256) void wconv_kernel(
    const float* __restrict__ W, int K, unsigned short* __restrict__ Wt) {
  int idx = blockIdx.x * 256 + threadIdx.x;
  if (idx >= K * 256) return;
  int k = idx >> 8, n = idx & 255;
  Wt[n * K + k] = f2bf(W[idx]);
}

// ------- MFMA matmul: out(bf16)[M,512] = A(bf16) @ Wcat (bias on cols<256) -------
// Wcat = [Wl ; Wr] as [512][K] k-contiguous rows. Block 128 rows x 128 cols,
// blockIdx.y in 0..3. 4 waves (2x2), each 64x64 = 4x4 tiles of 16x16x32.
template <int K>
__global__ __launch_bounds__(256) void matmul_mfma_kernel(
    const unsigned short* __restrict__ A, const unsigned short* __restrict__ Wt,
    const float* __restrict__ bias, unsigned short* __restrict__ out, int M) {
  constexpr int AP = 40;                 // LDS k-stride (shorts): 80B, 16B-aligned
  __shared__ unsigned short a_lds[128 * AP];
  __shared__ unsigned short b_lds[128 * AP];
  const int tid = threadIdx.x;
  const int wave = tid >> 6;
  const int lane = tid & 63;
  const int quad = lane >> 4;
  const int lrow = lane & 15;
  const int wr = (wave & 1) * 64;
  const int wc = (wave >> 1) * 64;
  const int r0 = blockIdx.x * 128;
  const int n0 = blockIdx.y * 128;       // 0..384 over the 512-wide output

  f32x4 acc[4][4];
#pragma unroll
  for (int i = 0; i < 4; ++i)
#pragma unroll
    for (int j = 0; j < 4; ++j) acc[i][j] = (f32x4){0.f, 0.f, 0.f, 0.f};

  const int srow = tid >> 1;
  const int shalf = tid & 1;
  int agrow = r0 + srow; if (agrow >= M) agrow = M - 1;   // clamp; stores guarded
  const int bgrow = n0 + srow;

  for (int k0 = 0; k0 < K; k0 += 32) {
    {
      const float4* sa = (const float4*)&A[(size_t)agrow * K + k0 + shalf * 16];
      const float4* sb = (const float4*)&Wt[(size_t)bgrow * K + k0 + shalf * 16];
      float4 va0 = sa[0], va1 = sa[1];
      float4 vb0 = sb[0], vb1 = sb[1];
      *(float4*)&a_lds[srow * AP + shalf * 16]     = va0;
      *(float4*)&a_lds[srow * AP + shalf * 16 + 8] = va1;
      *(float4*)&b_lds[srow * AP + shalf * 16]     = vb0;
      *(float4*)&b_lds[srow * AP + shalf * 16 + 8] = vb1;
    }
    __syncthreads();

    v8s af[4], bf[4];
#pragma unroll
    for (int rt = 0; rt < 4; ++rt)
      af[rt] = *(const v8s*)&a_lds[(wr + rt * 16 + lrow) * AP + quad * 8];
#pragma unroll
    for (int ct = 0; ct < 4; ++ct)
      bf[ct] = *(const v8s*)&b_lds[(wc + ct * 16 + lrow) * AP + quad * 8];
#pragma unroll
    for (int rt = 0; rt < 4; ++rt)
#pragma unroll
      for (int ct = 0; ct < 4; ++ct)
        acc[rt][ct] = __builtin_amdgcn_mfma_f32_16x16x32_bf16(af[rt], bf[ct], acc[rt][ct], 0, 0, 0);
    __syncthreads();
  }

#pragma unroll
  for (int rt = 0; rt < 4; ++rt) {
    int mbase = r0 + wr + rt * 16 + quad * 4;
#pragma unroll
    for (int ct = 0; ct < 4; ++ct) {
      int col = n0 + wc + ct * 16 + lrow;
      float b = (col < 256) ? bias[col] : 0.f;   // bias only on the xl half
#pragma unroll
      for (int r = 0; r < 4; ++r) {
        int row = mbase + r;
        if (row < M) out[(size_t)row * 512 + col] = f2bf(acc[rt][ct][r] + b);
      }
    }
  }
}

// ---------------- CSR build ----------------
__global__ void degree_kernel(const int* __restrict__ ei, int* __restrict__ deg) {
  int e = blockIdx.x * 256 + threadIdx.x;
  if (e < NE) atomicAdd(&deg[ei[NE + e]], 1);
}

__global__ __launch_bounds__(256) void blocksum_kernel(
    const int* __restrict__ deg, int* __restrict__ bsum) {
  int t = threadIdx.x;
  int i = blockIdx.x * 256 + t;
  int v = (i < NN) ? deg[i] : 0;
#pragma unroll
  for (int off = 32; off; off >>= 1) v += __shfl_down(v, off, 64);
  __shared__ int ws[4];
  if ((t & 63) == 0) ws[t >> 6] = v;
  __syncthreads();
  if (t == 0) bsum[blockIdx.x] = ws[0] + ws[1] + ws[2] + ws[3];
}

__global__ __launch_bounds__(256) void blockscan_kernel(
    const int* __restrict__ bsum, int* __restrict__ bpre, int* __restrict__ rowstart) {
  __shared__ int s[256];
  int t = threadIdx.x;
  int v = (t < NB) ? bsum[t] : 0;
  s[t] = v;
  __syncthreads();
  for (int off = 1; off < 256; off <<= 1) {
    int x = s[t];
    int y = (t >= off) ? s[t - off] : 0;
    __syncthreads();
    s[t] = x + y;
    __syncthreads();
  }
  if (t < NB) bpre[t] = s[t] - v;
  if (t == 255) rowstart[NN] = s[255];
}

__global__ __launch_bounds__(256) void rowstart_kernel(
    const int* __restrict__ deg, const int* __restrict__ bpre,
    int* __restrict__ rowstart, int* __restrict__ cursor) {
  __shared__ int s[256];
  int t = threadIdx.x;
  int i = blockIdx.x * 256 + t;
  int v = (i < NN) ? deg[i] : 0;
  s[t] = v;
  __syncthreads();
  for (int off = 1; off < 256; off <<= 1) {
    int x = s[t];
    int y = (t >= off) ? s[t - off] : 0;
    __syncthreads();
    s[t] = x + y;
    __syncthreads();
  }
  if (i < NN) {
    int rs = bpre[blockIdx.x] + s[t] - v;
    rowstart[i] = rs;
    cursor[i] = rs;
  }
}

// CSR fill: single int2 (src, ea-bits) per edge -> one aligned 8B scatter store.
__global__ void fill_kernel(const int* __restrict__ ei, const float* __restrict__ ea,
                            int* __restrict__ cursor, int2* __restrict__ edges) {
  int e = blockIdx.x * 256 + threadIdx.x;
  if (e < NE) {
    int d = ei[NE + e];
    int pos = atomicAdd(&cursor[d], 1);
    edges[pos] = make_int2(ei[e], __float_as_int(ea[e]));
  }
}

// ---------------- fused GATv2 edge phase: wave per dst node ----------------
// xlr is [N][512] bf16: xl = row cols 0..255, xr = cols 256..511 (uint2 +64).
// Scalarized edge metadata (s_load), 8 gathers in flight, leaky = max(s,0.2s),
// exp via exp2 (att pre-scaled by log2 e).
// POOL=false: write relu(out) bf16 [N,256] (A of next matmul).
// POOL=true : LDS-reduce the block's 4 node vectors by graph run (batch sorted)
//             and atomicAdd into pool[GG,256] — replaces hbuf + pool_kernel.
template <bool POOL>
__global__ __launch_bounds__(256) void gat_fused_kernel(
    const int* __restrict__ rowstart, const int2* __restrict__ edges,
    const unsigned short* __restrict__ xlr,
    const float* __restrict__ we, const float* __restrict__ att,
    const float* __restrict__ bias, const int* __restrict__ batch,
    unsigned short* __restrict__ outb, float* __restrict__ pool) {
  int wave = threadIdx.x >> 6;
  int node = blockIdx.x * 4 + wave;
  int lane = threadIdx.x & 63;
  int r0 = __builtin_amdgcn_readfirstlane(rowstart[node]);
  int r1 = __builtin_amdgcn_readfirstlane(rowstart[node + 1]);
  const uint2* xlr2 = (const uint2*)xlr;
  uint2 rp = xlr2[(size_t)node * 128 + 64 + lane];
  float4 r = make_float4(bflo(rp.x), bfhi(rp.x), bflo(rp.y), bfhi(rp.y));
  float4 wv = ((const float4*)we)[lane];
  float4 at = ((const float4*)att)[lane];
  const float LOG2E = 1.442695040888963f;
  at.x *= LOG2E; at.y *= LOG2E; at.z *= LOG2E; at.w *= LOG2E;
  float4 acc = make_float4(0.f, 0.f, 0.f, 0.f);
  float denom = 0.f;

  auto edge_step = [&](float eav, uint2 p) {
    float4 a = make_float4(bflo(p.x), bfhi(p.x), bflo(p.y), bfhi(p.y));
    float s0 = a.x + (r.x + eav * wv.x);
    float s1 = a.y + (r.y + eav * wv.y);
    float s2 = a.z + (r.z + eav * wv.z);
    float s3 = a.w + (r.w + eav * wv.w);
    s0 = fmaxf(s0, 0.2f * s0);
    s1 = fmaxf(s1, 0.2f * s1);
    s2 = fmaxf(s2, 0.2f * s2);
    s3 = fmaxf(s3, 0.2f * s3);
    float p4 = (s0 * at.x + s1 * at.y) + (s2 * at.z + s3 * at.w);
#pragma unroll
    for (int off = 8; off; off >>= 1) p4 += __shfl_xor(p4, off, 16);
    float ex = exp2f(p4);
    denom += ex;
    acc.x += ex * a.x; acc.y += ex * a.y; acc.z += ex * a.z; acc.w += ex * a.w;
  };

  int i = r0;
  for (; i + 8 <= r1; i += 8) {           // 8 gathers in flight
    int2 e0 = edges[i];     int2 e1 = edges[i + 1];
    int2 e2 = edges[i + 2]; int2 e3 = edges[i + 3];
    int2 e4 = edges[i + 4]; int2 e5 = edges[i + 5];
    int2 e6 = edges[i + 6]; int2 e7 = edges[i + 7];
    uint2 p0 = xlr2[(size_t)e0.x * 128 + lane];
    uint2 p1 = xlr2[(size_t)e1.x * 128 + lane];
    uint2 p2 = xlr2[(size_t)e2.x * 128 + lane];
    uint2 p3 = xlr2[(size_t)e3.x * 128 + lane];
    uint2 p4 = xlr2[(size_t)e4.x * 128 + lane];
    uint2 p5 = xlr2[(size_t)e5.x * 128 + lane];
    uint2 p6 = xlr2[(size_t)e6.x * 128 + lane];
    uint2 p7 = xlr2[(size_t)e7.x * 128 + lane];
    edge_step(__int_as_float(e0.y), p0);
    edge_step(__int_as_float(e1.y), p1);
    edge_step(__int_as_float(e2.y), p2);
    edge_step(__int_as_float(e3.y), p3);
    edge_step(__int_as_float(e4.y), p4);
    edge_step(__int_as_float(e5.y), p5);
    edge_step(__int_as_float(e6.y), p6);
    edge_step(__int_as_float(e7.y), p7);
  }
  for (; i + 4 <= r1; i += 4) {
    int2 e0 = edges[i];     int2 e1 = edges[i + 1];
    int2 e2 = edges[i + 2]; int2 e3 = edges[i + 3];
    uint2 p0 = xlr2[(size_t)e0.x * 128 + lane];
    uint2 p1 = xlr2[(size_t)e1.x * 128 + lane];
    uint2 p2 = xlr2[(size_t)e2.x * 128 + lane];
    uint2 p3 = xlr2[(size_t)e3.x * 128 + lane];
    edge_step(__int_as_float(e0.y), p0);
    edge_step(__int_as_float(e1.y), p1);
    edge_step(__int_as_float(e2.y), p2);
    edge_step(__int_as_float(e3.y), p3);
  }
  for (; i < r1; ++i) {
    int2 e = edges[i];
    edge_step(__int_as_float(e.y), xlr2[(size_t)e.x * 128 + lane]);
  }

  float inv = 1.f / (denom + 1e-16f);
  float4 bv = ((const float4*)bias)[lane];
  float4 o;
  o.x = fmaxf(acc.x * inv + bv.x, 0.f);
  o.y = fmaxf(acc.y * inv + bv.y, 0.f);
  o.z = fmaxf(acc.z * inv + bv.z, 0.f);
  o.w = fmaxf(acc.w * inv + bv.w, 0.f);

  if (!POOL) {
    uint2 pk;
    pk.x = (unsigned)f2bf(o.x) | ((unsigned)f2bf(o.y) << 16);
    pk.y = (unsigned)f2bf(o.z) | ((unsigned)f2bf(o.w) << 16);
    ((uint2*)outb)[(size_t)node * 64 + lane] = pk;
  } else {
    __shared__ float so[4][256];
    __shared__ int sg[4];
    *(float4*)&so[wave][lane * 4] = o;
    if (lane == 0) sg[wave] = batch[node];
    __syncthreads();
    int tid = threadIdx.x;
    if (tid < 256) {   // 256 threads: channel tid, run-length over the 4 nodes
      float a = so[0][tid];
      int cg = sg[0];
#pragma unroll
      for (int w = 1; w < 4; ++w) {
        if (sg[w] == cg) {
          a += so[w][tid];
        } else {
          atomicAdd(&pool[cg * 256 + tid], a);
          cg = sg[w];
          a = so[w][tid];
        }
      }
      atomicAdd(&pool[cg * 256 + tid], a);
    }
  }
}

// ---------------- segment bounds via binary search (batch is sorted) ----------------
__global__ void seg_bounds_kernel(const int* __restrict__ batch, int* __restrict__ bounds) {
  int g = threadIdx.x;                 // 0..GG inclusive
  if (g > GG) return;
  int lo = 0, hi = NN;
  while (lo < hi) {
    int mid = (lo + hi) >> 1;
    if (batch[mid] < g) lo = mid + 1; else hi = mid;
  }
  bounds[g] = lo;
}

// ---------------- final MLP: one block (128 thr) per graph ----------------
__global__ __launch_bounds__(128) void mlp_kernel(
    const float* __restrict__ pool, const int* __restrict__ bounds,
    const float* __restrict__ p1w, const float* __restrict__ p1b,
    const float* __restrict__ lng, const float* __restrict__ lnb,
    const float* __restrict__ p2w, const float* __restrict__ p2b,
    const float* __restrict__ hw, const float* __restrict__ hb,
    float* __restrict__ out) {
  __shared__ float sg[256];
  __shared__ float red[128];
  __shared__ float sz[128];
  __shared__ float s2[64];
  int b = blockIdx.x, tid = threadIdx.x;
  float cntf = (float)(bounds[b + 1] - bounds[b]);
  float invc = 1.f / fmaxf(cntf, 1.f);
  for (int i = tid; i < 256; i += 128) sg[i] = pool[b * 256 + i] * invc;
  __syncthreads();
  float z = p1b[tid];
  for (int k = 0; k < 256; ++k) z += sg[k] * p1w[k * 128 + tid];
  red[tid] = z; __syncthreads();
  for (int off = 64; off; off >>= 1) { if (tid < off) red[tid] += red[tid + off]; __syncthreads(); }
  float mu = red[0] * (1.f / 128.f);
  __syncthreads();
  float d = z - mu;
  red[tid] = d * d; __syncthreads();
  for (int off = 64; off; off >>= 1) { if (tid < off) red[tid] += red[tid + off]; __syncthreads(); }
  float var = red[0] * (1.f / 128.f);
  float zn = d * rsqrtf(var + 1e-5f) * lng[tid] + lnb[tid];
  sz[tid] = fmaxf(zn, 0.f);
  __syncthreads();
  if (tid < 64) {
    float a = p2b[tid];
    for (int k = 0; k < 128; ++k) a += sz[k] * p2w[k * 64 + tid];
    s2[tid] = fmaxf(a, 0.f);
  }
  __syncthreads();
  if (tid < 64) {
    float p = s2[tid] * hw[tid];
    for (int off = 32; off; off >>= 1) p += __shfl_down(p, off, 64);
    if (tid == 0) out[b] = p + hb[0];
  }
}

extern "C" void kernel_launch(void* const* d_in, const int* in_sizes, int n_in,
                              void* d_out, int out_size, void* d_ws, size_t ws_size,
                              hipStream_t stream) {
  const float* x      = (const float*)d_in[0];
  const int*   ei     = (const int*)d_in[1];
  const float* ea     = (const float*)d_in[2];
  const int*   batch  = (const int*)d_in[3];
  const float* enc_w  = (const float*)d_in[4];
  const float* enc_b  = (const float*)d_in[5];
  const float* g1_wl  = (const float*)d_in[6];
  const float* g1_bl  = (const float*)d_in[7];
  const float* g1_wr  = (const float*)d_in[8];
  const float* g1_we  = (const float*)d_in[9];
  const float* g1_att = (const float*)d_in[10];
  const float* g1_b   = (const float*)d_in[11];
  const float* g2_wl  = (const float*)d_in[12];
  const float* g2_bl  = (const float*)d_in[13];
  const float* g2_wr  = (const float*)d_in[14];
  const float* g2_we  = (const float*)d_in[15];
  const float* g2_att = (const float*)d_in[16];
  const float* g2_b   = (const float*)d_in[17];
  const float* p1_w   = (const float*)d_in[18];
  const float* p1_b   = (const float*)d_in[19];
  const float* ln_g   = (const float*)d_in[20];
  const float* ln_b   = (const float*)d_in[21];
  const float* p2_w   = (const float*)d_in[22];
  const float* p2_b   = (const float*)d_in[23];
  const float* head_w = (const float*)d_in[24];
  const float* head_b = (const float*)d_in[25];
  float* out = (float*)d_out;

  char* ws = (char*)d_ws;
  size_t off = 0;
  auto alloc = [&](size_t bytes) -> void* {
    void* p = ws + off;
    off = (off + bytes + 255) & ~(size_t)255;
    return p;
  };
  unsigned short* xlr  = (unsigned short*)alloc((size_t)NN * 512 * 2);
  unsigned short* h0   = (unsigned short*)alloc((size_t)NN * 64 * 2);
  unsigned short* hb16 = (unsigned short*)alloc((size_t)NN * HC * 2);
  unsigned short* wt1  = (unsigned short*)alloc((size_t)512 * 64 * 2);
  unsigned short* wt2  = (unsigned short*)alloc((size_t)512 * 256 * 2);
  float* pool      = (float*)alloc((size_t)GG * HC * 4);
  int*   deg       = (int*)alloc((size_t)NN * 4);
  int*   rowstart  = (int*)alloc((size_t)(NN + 1) * 4);
  int*   cursor    = (int*)alloc((size_t)NN * 4);
  int*   bsum      = (int*)alloc((size_t)NB * 4);
  int*   bpre      = (int*)alloc((size_t)NB * 4);
  int2*  edges     = (int2*)alloc((size_t)NE * 8);
  int*   bounds    = (int*)alloc((size_t)(GG + 1) * 4);

  hipMemsetAsync(deg, 0, (size_t)NN * 4, stream);
  hipMemsetAsync(pool, 0, (size_t)GG * HC * 4, stream);

  // encoder (bf16 out) + weight prep (concatenated [512][K] layouts)
  encoder_kernel<<<NN * 64 / 256, 256, 0, stream>>>(x, enc_w, enc_b, h0);
  wconv_kernel<<<64, 256, 0, stream>>>(g1_wl, 64, wt1);
  wconv_kernel<<<64, 256, 0, stream>>>(g1_wr, 64, wt1 + (size_t)256 * 64);
  wconv_kernel<<<256, 256, 0, stream>>>(g2_wl, 256, wt2);
  wconv_kernel<<<256, 256, 0, stream>>>(g2_wr, 256, wt2 + (size_t)256 * 256);

  // CSR build: degree -> hierarchical scan -> fill
  degree_kernel<<<(NE + 255) / 256, 256, 0, stream>>>(ei, deg);
  blocksum_kernel<<<NB, 256, 0, stream>>>(deg, bsum);
  blockscan_kernel<<<1, 256, 0, stream>>>(bsum, bpre, rowstart);
  rowstart_kernel<<<NB, 256, 0, stream>>>(deg, bpre, rowstart, cursor);
  fill_kernel<<<(NE + 255) / 256, 256, 0, stream>>>(ei, ea, cursor, edges);

  // graph segment bounds (batch is sorted)
  seg_bounds_kernel<<<1, GG + 1, 0, stream>>>(batch, bounds);

  dim3 mmg((NN + 127) / 128, 4);   // 391 x 4 blocks, [M,512] output

  // ---- GAT layer 1 (K=64): one fused xl|xr matmul, then edge phase ----
  matmul_mfma_kernel<64><<<mmg, 256, 0, stream>>>(h0, wt1, g1_bl, xlr, NN);
  gat_fused_kernel<false><<<NN / 4, 256, 0, stream>>>(rowstart, edges, xlr,
                                                      g1_we, g1_att, g1_b, batch,
                                                      hb16, nullptr);

  // ---- GAT layer 2 (K=256): fused matmul, then edge phase + fused pooling ----
  matmul_mfma_kernel<256><<<mmg, 256, 0, stream>>>(hb16, wt2, g2_bl, xlr, NN);
  gat_fused_kernel<true><<<NN / 4, 256, 0, stream>>>(rowstart, edges, xlr,
                                                     g2_we, g2_att, g2_b, batch,
                                                     nullptr, pool);

  // ---- MLP head ----
  mlp_kernel<<<GG, 128, 0, stream>>>(pool, bounds, p1_w, p1_b, ln_g, ln_b,
                                     p2_w, p2_b, head_w, head_b, out);
}

// Round 18
// 377.172 us; speedup vs baseline: 1.0434x; 1.0434x over previous
//
#include <hip/hip_runtime.h>
#include <hip/hip_bf16.h>
#include <math.h>

#define NN 50000     // nodes
#define NE 400000    // edges
#define HH 4         // heads
#define CC 64        // per-head dim
#define HC 256       // H*C
#define GG 64        // graphs
#define NB 196       // scan blocks: ceil(NN/256)

typedef short v8s __attribute__((ext_vector_type(8)));
typedef float f32x4 __attribute__((ext_vector_type(4)));

static __device__ inline unsigned short f2bf(float v) {
  __hip_bfloat16 b = __float2bfloat16(v);
  return *reinterpret_cast<unsigned short*>(&b);
}
// packed bf16 pair -> f32 (bf16 value = bit pattern << 16)
static __device__ inline float bflo(unsigned u) { return __uint_as_float(u << 16); }
static __device__ inline float bfhi(unsigned u) { return __uint_as_float(u & 0xffff0000u); }

// ---------------- encoder: h0 = relu(x @ enc_w + enc_b) -> bf16 ----------------
__global__ __launch_bounds__(256) void encoder_kernel(
    const float* __restrict__ x, const float* __restrict__ w,
    const float* __restrict__ b, unsigned short* __restrict__ h0) {
  int idx = blockIdx.x * 256 + threadIdx.x;   // N*64 threads
  int node = idx >> 6, col = idx & 63;
  const float* xr = x + node * 8;
  float acc = b[col];
#pragma unroll
  for (int k = 0; k < 8; ++k) acc += xr[k] * w[k * 64 + col];
  h0[idx] = f2bf(fmaxf(acc, 0.f));
}

// ---- W prep: W[K,256] f32 -> Wt bf16 [256][K] (k-contiguous rows) ----
__global__ __launch_bounds__(256) void wconv_kernel(
    const float* __restrict__ W, int K, unsigned short* __restrict__ Wt) {
  int idx = blockIdx.x * 256 + threadIdx.x;
  if (idx >= K * 256) return;
  int k = idx >> 8, n = idx & 255;
  Wt[n * K + k] = f2bf(W[idx]);
}

// ------- MFMA matmul: {xl,xr}(bf16)[M,256] = A(bf16) @ [Wl;Wr] (bias on xl) -------
// Wcat = [512][K] k-contiguous rows. Block 128 rows x 128 cols, blockIdx.y 0..3:
// y<2 -> xl half, y>=2 -> xr half (base pointer wave-uniform; separate output
// arrays keep the round-16 gather layout). A tile staged once serves both halves
// across the y-grid via L2.
template <int K>
__global__ __launch_bounds__(256) void matmul_mfma_kernel(
    const unsigned short* __restrict__ A, const unsigned short* __restrict__ Wt,
    const float* __restrict__ bias,
    unsigned short* __restrict__ outL, unsigned short* __restrict__ outR, int M) {
  constexpr int AP = 40;                 // LDS k-stride (shorts): 80B, 16B-aligned
  __shared__ unsigned short a_lds[128 * AP];
  __shared__ unsigned short b_lds[128 * AP];
  const int tid = threadIdx.x;
  const int wave = tid >> 6;
  const int lane = tid & 63;
  const int quad = lane >> 4;
  const int lrow = lane & 15;
  const int wr = (wave & 1) * 64;
  const int wc = (wave >> 1) * 64;
  const int r0 = blockIdx.x * 128;
  const int n0 = blockIdx.y * 128;       // 0..384 over the 512 concat cols

  f32x4 acc[4][4];
#pragma unroll
  for (int i = 0; i < 4; ++i)
#pragma unroll
    for (int j = 0; j < 4; ++j) acc[i][j] = (f32x4){0.f, 0.f, 0.f, 0.f};

  const int srow = tid >> 1;
  const int shalf = tid & 1;
  int agrow = r0 + srow; if (agrow >= M) agrow = M - 1;   // clamp; stores guarded
  const int bgrow = n0 + srow;

  for (int k0 = 0; k0 < K; k0 += 32) {
    {
      const float4* sa = (const float4*)&A[(size_t)agrow * K + k0 + shalf * 16];
      const float4* sb = (const float4*)&Wt[(size_t)bgrow * K + k0 + shalf * 16];
      float4 va0 = sa[0], va1 = sa[1];
      float4 vb0 = sb[0], vb1 = sb[1];
      *(float4*)&a_lds[srow * AP + shalf * 16]     = va0;
      *(float4*)&a_lds[srow * AP + shalf * 16 + 8] = va1;
      *(float4*)&b_lds[srow * AP + shalf * 16]     = vb0;
      *(float4*)&b_lds[srow * AP + shalf * 16 + 8] = vb1;
    }
    __syncthreads();

    v8s af[4], bf[4];
#pragma unroll
    for (int rt = 0; rt < 4; ++rt)
      af[rt] = *(const v8s*)&a_lds[(wr + rt * 16 + lrow) * AP + quad * 8];
#pragma unroll
    for (int ct = 0; ct < 4; ++ct)
      bf[ct] = *(const v8s*)&b_lds[(wc + ct * 16 + lrow) * AP + quad * 8];
#pragma unroll
    for (int rt = 0; rt < 4; ++rt)
#pragma unroll
      for (int ct = 0; ct < 4; ++ct)
        acc[rt][ct] = __builtin_amdgcn_mfma_f32_16x16x32_bf16(af[rt], bf[ct], acc[rt][ct], 0, 0, 0);
    __syncthreads();
  }

  const bool isL = (n0 < 256);
  unsigned short* outp = isL ? outL : outR;
  const int cbase = isL ? n0 : (n0 - 256);
#pragma unroll
  for (int rt = 0; rt < 4; ++rt) {
    int mbase = r0 + wr + rt * 16 + quad * 4;
#pragma unroll
    for (int ct = 0; ct < 4; ++ct) {
      int col = cbase + wc + ct * 16 + lrow;
      float b = isL ? bias[col] : 0.f;
#pragma unroll
      for (int r = 0; r < 4; ++r) {
        int row = mbase + r;
        if (row < M) outp[(size_t)row * 256 + col] = f2bf(acc[rt][ct][r] + b);
      }
    }
  }
}

// ---------------- CSR build ----------------
__global__ void degree_kernel(const int* __restrict__ ei, int* __restrict__ deg) {
  int e = blockIdx.x * 256 + threadIdx.x;
  if (e < NE) atomicAdd(&deg[ei[NE + e]], 1);
}

__global__ __launch_bounds__(256) void blocksum_kernel(
    const int* __restrict__ deg, int* __restrict__ bsum) {
  int t = threadIdx.x;
  int i = blockIdx.x * 256 + t;
  int v = (i < NN) ? deg[i] : 0;
#pragma unroll
  for (int off = 32; off; off >>= 1) v += __shfl_down(v, off, 64);
  __shared__ int ws[4];
  if ((t & 63) == 0) ws[t >> 6] = v;
  __syncthreads();
  if (t == 0) bsum[blockIdx.x] = ws[0] + ws[1] + ws[2] + ws[3];
}

__global__ __launch_bounds__(256) void blockscan_kernel(
    const int* __restrict__ bsum, int* __restrict__ bpre, int* __restrict__ rowstart) {
  __shared__ int s[256];
  int t = threadIdx.x;
  int v = (t < NB) ? bsum[t] : 0;
  s[t] = v;
  __syncthreads();
  for (int off = 1; off < 256; off <<= 1) {
    int x = s[t];
    int y = (t >= off) ? s[t - off] : 0;
    __syncthreads();
    s[t] = x + y;
    __syncthreads();
  }
  if (t < NB) bpre[t] = s[t] - v;
  if (t == 255) rowstart[NN] = s[255];
}

__global__ __launch_bounds__(256) void rowstart_kernel(
    const int* __restrict__ deg, const int* __restrict__ bpre,
    int* __restrict__ rowstart, int* __restrict__ cursor) {
  __shared__ int s[256];
  int t = threadIdx.x;
  int i = blockIdx.x * 256 + t;
  int v = (i < NN) ? deg[i] : 0;
  s[t] = v;
  __syncthreads();
  for (int off = 1; off < 256; off <<= 1) {
    int x = s[t];
    int y = (t >= off) ? s[t - off] : 0;
    __syncthreads();
    s[t] = x + y;
    __syncthreads();
  }
  if (i < NN) {
    int rs = bpre[blockIdx.x] + s[t] - v;
    rowstart[i] = rs;
    cursor[i] = rs;
  }
}

// CSR fill: single int2 (src, ea-bits) per edge -> one aligned 8B scatter store.
__global__ void fill_kernel(const int* __restrict__ ei, const float* __restrict__ ea,
                            int* __restrict__ cursor, int2* __restrict__ edges) {
  int e = blockIdx.x * 256 + threadIdx.x;
  if (e < NE) {
    int d = ei[NE + e];
    int pos = atomicAdd(&cursor[d], 1);
    edges[pos] = make_int2(ei[e], __float_as_int(ea[e]));
  }
}

// ---------------- fused GATv2 edge phase: wave per dst node (round-16 body) ----
// POOL=false: write relu(out) bf16 [N,256]. POOL=true: LDS-reduce the block's 4
// node vectors by graph run (batch sorted) and atomicAdd into pool[GG,256].
template <bool POOL>
__global__ __launch_bounds__(256) void gat_fused_kernel(
    const int* __restrict__ rowstart, const int2* __restrict__ edges,
    const unsigned short* __restrict__ xl, const unsigned short* __restrict__ xr,
    const float* __restrict__ we, const float* __restrict__ att,
    const float* __restrict__ bias, const int* __restrict__ batch,
    unsigned short* __restrict__ outb, float* __restrict__ pool) {
  int wave = threadIdx.x >> 6;
  int node = blockIdx.x * 4 + wave;
  int lane = threadIdx.x & 63;
  int r0 = __builtin_amdgcn_readfirstlane(rowstart[node]);
  int r1 = __builtin_amdgcn_readfirstlane(rowstart[node + 1]);
  const uint2* xl2 = (const uint2*)xl;
  uint2 rp = ((const uint2*)xr)[(size_t)node * 64 + lane];
  float4 r = make_float4(bflo(rp.x), bfhi(rp.x), bflo(rp.y), bfhi(rp.y));
  float4 wv = ((const float4*)we)[lane];
  float4 at = ((const float4*)att)[lane];
  const float LOG2E = 1.442695040888963f;
  at.x *= LOG2E; at.y *= LOG2E; at.z *= LOG2E; at.w *= LOG2E;
  float4 acc = make_float4(0.f, 0.f, 0.f, 0.f);
  float denom = 0.f;

  auto edge_step = [&](float eav, uint2 p) {
    float4 a = make_float4(bflo(p.x), bfhi(p.x), bflo(p.y), bfhi(p.y));
    float s0 = a.x + (r.x + eav * wv.x);
    float s1 = a.y + (r.y + eav * wv.y);
    float s2 = a.z + (r.z + eav * wv.z);
    float s3 = a.w + (r.w + eav * wv.w);
    s0 = fmaxf(s0, 0.2f * s0);
    s1 = fmaxf(s1, 0.2f * s1);
    s2 = fmaxf(s2, 0.2f * s2);
    s3 = fmaxf(s3, 0.2f * s3);
    float p4 = (s0 * at.x + s1 * at.y) + (s2 * at.z + s3 * at.w);
#pragma unroll
    for (int off = 8; off; off >>= 1) p4 += __shfl_xor(p4, off, 16);
    float ex = exp2f(p4);
    denom += ex;
    acc.x += ex * a.x; acc.y += ex * a.y; acc.z += ex * a.z; acc.w += ex * a.w;
  };

  int i = r0;
  for (; i + 4 <= r1; i += 4) {           // 4 gathers in flight (proven schedule)
    int2 e0 = edges[i];     int2 e1 = edges[i + 1];
    int2 e2 = edges[i + 2]; int2 e3 = edges[i + 3];
    uint2 p0 = xl2[(size_t)e0.x * 64 + lane];
    uint2 p1 = xl2[(size_t)e1.x * 64 + lane];
    uint2 p2 = xl2[(size_t)e2.x * 64 + lane];
    uint2 p3 = xl2[(size_t)e3.x * 64 + lane];
    edge_step(__int_as_float(e0.y), p0);
    edge_step(__int_as_float(e1.y), p1);
    edge_step(__int_as_float(e2.y), p2);
    edge_step(__int_as_float(e3.y), p3);
  }
  for (; i < r1; ++i) {
    int2 e = edges[i];
    edge_step(__int_as_float(e.y), xl2[(size_t)e.x * 64 + lane]);
  }

  float inv = 1.f / (denom + 1e-16f);
  float4 bv = ((const float4*)bias)[lane];
  float4 o;
  o.x = fmaxf(acc.x * inv + bv.x, 0.f);
  o.y = fmaxf(acc.y * inv + bv.y, 0.f);
  o.z = fmaxf(acc.z * inv + bv.z, 0.f);
  o.w = fmaxf(acc.w * inv + bv.w, 0.f);

  if (!POOL) {
    uint2 pk;
    pk.x = (unsigned)f2bf(o.x) | ((unsigned)f2bf(o.y) << 16);
    pk.y = (unsigned)f2bf(o.z) | ((unsigned)f2bf(o.w) << 16);
    ((uint2*)outb)[(size_t)node * 64 + lane] = pk;
  } else {
    __shared__ float so[4][256];
    __shared__ int sg[4];
    *(float4*)&so[wave][lane * 4] = o;
    if (lane == 0) sg[wave] = batch[node];
    __syncthreads();
    int tid = threadIdx.x;   // 256 threads: channel tid, run-length over 4 nodes
    float a = so[0][tid];
    int cg = sg[0];
#pragma unroll
    for (int w = 1; w < 4; ++w) {
      if (sg[w] == cg) {
        a += so[w][tid];
      } else {
        atomicAdd(&pool[cg * 256 + tid], a);
        cg = sg[w];
        a = so[w][tid];
      }
    }
    atomicAdd(&pool[cg * 256 + tid], a);
  }
}

// ---------------- segment bounds via binary search (batch is sorted) ----------------
__global__ void seg_bounds_kernel(const int* __restrict__ batch, int* __restrict__ bounds) {
  int g = threadIdx.x;                 // 0..GG inclusive
  if (g > GG) return;
  int lo = 0, hi = NN;
  while (lo < hi) {
    int mid = (lo + hi) >> 1;
    if (batch[mid] < g) lo = mid + 1; else hi = mid;
  }
  bounds[g] = lo;
}

// ---------------- final MLP: one block (128 thr) per graph ----------------
__global__ __launch_bounds__(128) void mlp_kernel(
    const float* __restrict__ pool, const int* __restrict__ bounds,
    const float* __restrict__ p1w, const float* __restrict__ p1b,
    const float* __restrict__ lng, const float* __restrict__ lnb,
    const float* __restrict__ p2w, const float* __restrict__ p2b,
    const float* __restrict__ hw, const float* __restrict__ hb,
    float* __restrict__ out) {
  __shared__ float sg[256];
  __shared__ float red[128];
  __shared__ float sz[128];
  __shared__ float s2[64];
  int b = blockIdx.x, tid = threadIdx.x;
  float cntf = (float)(bounds[b + 1] - bounds[b]);
  float invc = 1.f / fmaxf(cntf, 1.f);
  for (int i = tid; i < 256; i += 128) sg[i] = pool[b * 256 + i] * invc;
  __syncthreads();
  float z = p1b[tid];
  for (int k = 0; k < 256; ++k) z += sg[k] * p1w[k * 128 + tid];
  red[tid] = z; __syncthreads();
  for (int off = 64; off; off >>= 1) { if (tid < off) red[tid] += red[tid + off]; __syncthreads(); }
  float mu = red[0] * (1.f / 128.f);
  __syncthreads();
  float d = z - mu;
  red[tid] = d * d; __syncthreads();
  for (int off = 64; off; off >>= 1) { if (tid < off) red[tid] += red[tid + off]; __syncthreads(); }
  float var = red[0] * (1.f / 128.f);
  float zn = d * rsqrtf(var + 1e-5f) * lng[tid] + lnb[tid];
  sz[tid] = fmaxf(zn, 0.f);
  __syncthreads();
  if (tid < 64) {
    float a = p2b[tid];
    for (int k = 0; k < 128; ++k) a += sz[k] * p2w[k * 64 + tid];
    s2[tid] = fmaxf(a, 0.f);
  }
  __syncthreads();
  if (tid < 64) {
    float p = s2[tid] * hw[tid];
    for (int off = 32; off; off >>= 1) p += __shfl_down(p, off, 64);
    if (tid == 0) out[b] = p + hb[0];
  }
}

extern "C" void kernel_launch(void* const* d_in, const int* in_sizes, int n_in,
                              void* d_out, int out_size, void* d_ws, size_t ws_size,
                              hipStream_t stream) {
  const float* x      = (const float*)d_in[0];
  const int*   ei     = (const int*)d_in[1];
  const float* ea     = (const float*)d_in[2];
  const int*   batch  = (const int*)d_in[3];
  const float* enc_w  = (const float*)d_in[4];
  const float* enc_b  = (const float*)d_in[5];
  const float* g1_wl  = (const float*)d_in[6];
  const float* g1_bl  = (const float*)d_in[7];
  const float* g1_wr  = (const float*)d_in[8];
  const float* g1_we  = (const float*)d_in[9];
  const float* g1_att = (const float*)d_in[10];
  const float* g1_b   = (const float*)d_in[11];
  const float* g2_wl  = (const float*)d_in[12];
  const float* g2_bl  = (const float*)d_in[13];
  const float* g2_wr  = (const float*)d_in[14];
  const float* g2_we  = (const float*)d_in[15];
  const float* g2_att = (const float*)d_in[16];
  const float* g2_b   = (const float*)d_in[17];
  const float* p1_w   = (const float*)d_in[18];
  const float* p1_b   = (const float*)d_in[19];
  const float* ln_g   = (const float*)d_in[20];
  const float* ln_b   = (const float*)d_in[21];
  const float* p2_w   = (const float*)d_in[22];
  const float* p2_b   = (const float*)d_in[23];
  const float* head_w = (const float*)d_in[24];
  const float* head_b = (const float*)d_in[25];
  float* out = (float*)d_out;

  char* ws = (char*)d_ws;
  size_t off = 0;
  auto alloc = [&](size_t bytes) -> void* {
    void* p = ws + off;
    off = (off + bytes + 255) & ~(size_t)255;
    return p;
  };
  unsigned short* xl   = (unsigned short*)alloc((size_t)NN * HC * 2);
  unsigned short* xr   = (unsigned short*)alloc((size_t)NN * HC * 2);
  unsigned short* h0   = (unsigned short*)alloc((size_t)NN * 64 * 2);
  unsigned short* hb16 = (unsigned short*)alloc((size_t)NN * HC * 2);
  unsigned short* wt1  = (unsigned short*)alloc((size_t)512 * 64 * 2);
  unsigned short* wt2  = (unsigned short*)alloc((size_t)512 * 256 * 2);
  float* pool      = (float*)alloc((size_t)GG * HC * 4);
  int*   deg       = (int*)alloc((size_t)NN * 4);
  int*   rowstart  = (int*)alloc((size_t)(NN + 1) * 4);
  int*   cursor    = (int*)alloc((size_t)NN * 4);
  int*   bsum      = (int*)alloc((size_t)NB * 4);
  int*   bpre      = (int*)alloc((size_t)NB * 4);
  int2*  edges     = (int2*)alloc((size_t)NE * 8);
  int*   bounds    = (int*)alloc((size_t)(GG + 1) * 4);

  hipMemsetAsync(deg, 0, (size_t)NN * 4, stream);
  hipMemsetAsync(pool, 0, (size_t)GG * HC * 4, stream);

  // encoder (bf16 out) + weight prep (concatenated [512][K] layouts)
  encoder_kernel<<<NN * 64 / 256, 256, 0, stream>>>(x, enc_w, enc_b, h0);
  wconv_kernel<<<64, 256, 0, stream>>>(g1_wl, 64, wt1);
  wconv_kernel<<<64, 256, 0, stream>>>(g1_wr, 64, wt1 + (size_t)256 * 64);
  wconv_kernel<<<256, 256, 0, stream>>>(g2_wl, 256, wt2);
  wconv_kernel<<<256, 256, 0, stream>>>(g2_wr, 256, wt2 + (size_t)256 * 256);

  // CSR build: degree -> hierarchical scan -> fill
  degree_kernel<<<(NE + 255) / 256, 256, 0, stream>>>(ei, deg);
  blocksum_kernel<<<NB, 256, 0, stream>>>(deg, bsum);
  blockscan_kernel<<<1, 256, 0, stream>>>(bsum, bpre, rowstart);
  rowstart_kernel<<<NB, 256, 0, stream>>>(deg, bpre, rowstart, cursor);
  fill_kernel<<<(NE + 255) / 256, 256, 0, stream>>>(ei, ea, cursor, edges);

  // graph segment bounds (batch is sorted)
  seg_bounds_kernel<<<1, GG + 1, 0, stream>>>(batch, bounds);

  dim3 mmg((NN + 127) / 128, 4);   // 391 x 4 blocks over the 512 concat cols

  // ---- GAT layer 1 (K=64): one matmul launch -> separate xl/xr, then edges ----
  matmul_mfma_kernel<64><<<mmg, 256, 0, stream>>>(h0, wt1, g1_bl, xl, xr, NN);
  gat_fused_kernel<false><<<NN / 4, 256, 0, stream>>>(rowstart, edges, xl, xr,
                                                      g1_we, g1_att, g1_b, batch,
                                                      hb16, nullptr);

  // ---- GAT layer 2 (K=256): matmul, then edges + fused pooling ----
  matmul_mfma_kernel<256><<<mmg, 256, 0, stream>>>(hb16, wt2, g2_bl, xl, xr, NN);
  gat_fused_kernel<true><<<NN / 4, 256, 0, stream>>>(rowstart, edges, xl, xr,
                                                     g2_we, g2_att, g2_b, batch,
                                                     nullptr, pool);

  // ---- MLP head ----
  mlp_kernel<<<GG, 128, 0, stream>>>(pool, bounds, p1_w, p1_b, ln_g, ln_b,
                                     p2_w, p2_b, head_w, head_b, out);
}

// Round 19
// 376.749 us; speedup vs baseline: 1.0446x; 1.0011x over previous
//
#include <hip/hip_runtime.h>
#include <hip/hip_bf16.h>
#include <math.h>

#define NN 50000     // nodes
#define NE 400000    // edges
#define HH 4         // heads
#define CC 64        // per-head dim
#define HC 256       // H*C
#define GG 64        // graphs
#define NB 196       // scan blocks: ceil(NN/256)

typedef short v8s __attribute__((ext_vector_type(8)));
typedef float f32x4 __attribute__((ext_vector_type(4)));

static __device__ inline unsigned short f2bf(float v) {
  __hip_bfloat16 b = __float2bfloat16(v);
  return *reinterpret_cast<unsigned short*>(&b);
}
// packed bf16 pair -> f32 (bf16 value = bit pattern << 16)
static __device__ inline float bflo(unsigned u) { return __uint_as_float(u << 16); }
static __device__ inline float bfhi(unsigned u) { return __uint_as_float(u & 0xffff0000u); }

// ---------------- encoder: h0 = relu(x @ enc_w + enc_b) -> bf16 ----------------
__global__ __launch_bounds__(256) void encoder_kernel(
    const float* __restrict__ x, const float* __restrict__ w,
    const float* __restrict__ b, unsigned short* __restrict__ h0) {
  int idx = blockIdx.x * 256 + threadIdx.x;   // N*64 threads
  int node = idx >> 6, col = idx & 63;
  const float* xr = x + node * 8;
  float acc = b[col];
#pragma unroll
  for (int k = 0; k < 8; ++k) acc += xr[k] * w[k * 64 + col];
  h0[idx] = f2bf(fmaxf(acc, 0.f));
}

// ---- W prep: W[K,256] f32 -> Wt bf16 [256][K] (k-contiguous rows) ----
__global__ __launch_bounds__(256) void wconv_kernel(
    const float* __restrict__ W, int K, unsigned short* __restrict__ Wt) {
  int idx = blockIdx.x * 256 + threadIdx.x;
  if (idx >= K * 256) return;
  int k = idx >> 8, n = idx & 255;
  Wt[n * K + k] = f2bf(W[idx]);
}

// ------- MFMA matmul: {xl,xr}(bf16)[M,256] = A(bf16) @ [Wl;Wr] (bias on xl) -------
// Wcat = [512][K] k-contiguous rows. Block 128 rows x 128 cols, blockIdx.y 0..3:
// y<2 -> xl half, y>=2 -> xr half (wave-uniform base pointer).
template <int K>
__global__ __launch_bounds__(256) void matmul_mfma_kernel(
    const unsigned short* __restrict__ A, const unsigned short* __restrict__ Wt,
    const float* __restrict__ bias,
    unsigned short* __restrict__ outL, unsigned short* __restrict__ outR, int M) {
  constexpr int AP = 40;                 // LDS k-stride (shorts): 80B, 16B-aligned
  __shared__ unsigned short a_lds[128 * AP];
  __shared__ unsigned short b_lds[128 * AP];
  const int tid = threadIdx.x;
  const int wave = tid >> 6;
  const int lane = tid & 63;
  const int quad = lane >> 4;
  const int lrow = lane & 15;
  const int wr = (wave & 1) * 64;
  const int wc = (wave >> 1) * 64;
  const int r0 = blockIdx.x * 128;
  const int n0 = blockIdx.y * 128;       // 0..384 over the 512 concat cols

  f32x4 acc[4][4];
#pragma unroll
  for (int i = 0; i < 4; ++i)
#pragma unroll
    for (int j = 0; j < 4; ++j) acc[i][j] = (f32x4){0.f, 0.f, 0.f, 0.f};

  const int srow = tid >> 1;
  const int shalf = tid & 1;
  int agrow = r0 + srow; if (agrow >= M) agrow = M - 1;   // clamp; stores guarded
  const int bgrow = n0 + srow;

  for (int k0 = 0; k0 < K; k0 += 32) {
    {
      const float4* sa = (const float4*)&A[(size_t)agrow * K + k0 + shalf * 16];
      const float4* sb = (const float4*)&Wt[(size_t)bgrow * K + k0 + shalf * 16];
      float4 va0 = sa[0], va1 = sa[1];
      float4 vb0 = sb[0], vb1 = sb[1];
      *(float4*)&a_lds[srow * AP + shalf * 16]     = va0;
      *(float4*)&a_lds[srow * AP + shalf * 16 + 8] = va1;
      *(float4*)&b_lds[srow * AP + shalf * 16]     = vb0;
      *(float4*)&b_lds[srow * AP + shalf * 16 + 8] = vb1;
    }
    __syncthreads();

    v8s af[4], bf[4];
#pragma unroll
    for (int rt = 0; rt < 4; ++rt)
      af[rt] = *(const v8s*)&a_lds[(wr + rt * 16 + lrow) * AP + quad * 8];
#pragma unroll
    for (int ct = 0; ct < 4; ++ct)
      bf[ct] = *(const v8s*)&b_lds[(wc + ct * 16 + lrow) * AP + quad * 8];
#pragma unroll
    for (int rt = 0; rt < 4; ++rt)
#pragma unroll
      for (int ct = 0; ct < 4; ++ct)
        acc[rt][ct] = __builtin_amdgcn_mfma_f32_16x16x32_bf16(af[rt], bf[ct], acc[rt][ct], 0, 0, 0);
    __syncthreads();
  }

  const bool isL = (n0 < 256);
  unsigned short* outp = isL ? outL : outR;
  const int cbase = isL ? n0 : (n0 - 256);
#pragma unroll
  for (int rt = 0; rt < 4; ++rt) {
    int mbase = r0 + wr + rt * 16 + quad * 4;
#pragma unroll
    for (int ct = 0; ct < 4; ++ct) {
      int col = cbase + wc + ct * 16 + lrow;
      float b = isL ? bias[col] : 0.f;
#pragma unroll
      for (int r = 0; r < 4; ++r) {
        int row = mbase + r;
        if (row < M) outp[(size_t)row * 256 + col] = f2bf(acc[rt][ct][r] + b);
      }
    }
  }
}

// ---------------- CSR build ----------------
__global__ void degree_kernel(const int* __restrict__ ei, int* __restrict__ deg) {
  int e = blockIdx.x * 256 + threadIdx.x;
  if (e < NE) atomicAdd(&deg[ei[NE + e]], 1);
}

__global__ __launch_bounds__(256) void blocksum_kernel(
    const int* __restrict__ deg, int* __restrict__ bsum) {
  int t = threadIdx.x;
  int i = blockIdx.x * 256 + t;
  int v = (i < NN) ? deg[i] : 0;
#pragma unroll
  for (int off = 32; off; off >>= 1) v += __shfl_down(v, off, 64);
  __shared__ int ws[4];
  if ((t & 63) == 0) ws[t >> 6] = v;
  __syncthreads();
  if (t == 0) bsum[blockIdx.x] = ws[0] + ws[1] + ws[2] + ws[3];
}

__global__ __launch_bounds__(256) void blockscan_kernel(
    const int* __restrict__ bsum, int* __restrict__ bpre, int* __restrict__ rowstart) {
  __shared__ int s[256];
  int t = threadIdx.x;
  int v = (t < NB) ? bsum[t] : 0;
  s[t] = v;
  __syncthreads();
  for (int off = 1; off < 256; off <<= 1) {
    int x = s[t];
    int y = (t >= off) ? s[t - off] : 0;
    __syncthreads();
    s[t] = x + y;
    __syncthreads();
  }
  if (t < NB) bpre[t] = s[t] - v;
  if (t == 255) rowstart[NN] = s[255];
}

__global__ __launch_bounds__(256) void rowstart_kernel(
    const int* __restrict__ deg, const int* __restrict__ bpre,
    int* __restrict__ rowstart, int* __restrict__ cursor) {
  __shared__ int s[256];
  int t = threadIdx.x;
  int i = blockIdx.x * 256 + t;
  int v = (i < NN) ? deg[i] : 0;
  s[t] = v;
  __syncthreads();
  for (int off = 1; off < 256; off <<= 1) {
    int x = s[t];
    int y = (t >= off) ? s[t - off] : 0;
    __syncthreads();
    s[t] = x + y;
    __syncthreads();
  }
  if (i < NN) {
    int rs = bpre[blockIdx.x] + s[t] - v;
    rowstart[i] = rs;
    cursor[i] = rs;
  }
}

// CSR fill: single int2 (src, ea-bits) per edge -> one aligned 8B scatter store.
__global__ void fill_kernel(const int* __restrict__ ei, const float* __restrict__ ea,
                            int* __restrict__ cursor, int2* __restrict__ edges) {
  int e = blockIdx.x * 256 + threadIdx.x;
  if (e < NE) {
    int d = ei[NE + e];
    int pos = atomicAdd(&cursor[d], 1);
    edges[pos] = make_int2(ei[e], __float_as_int(ea[e]));
  }
}

// ---------------- fused GATv2 edge phase: wave per dst node (round-16 body) ----
// Scalarized edge metadata, 4 gathers in flight, leaky = max(s,0.2s), exp2.
// Always writes bf16 [N,256] (feeds next matmul OR the bf16 pool_kernel).
__global__ __launch_bounds__(256) void gat_fused_kernel(
    const int* __restrict__ rowstart, const int2* __restrict__ edges,
    const unsigned short* __restrict__ xl, const unsigned short* __restrict__ xr,
    const float* __restrict__ we, const float* __restrict__ att,
    const float* __restrict__ bias, unsigned short* __restrict__ outb) {
  int node = (blockIdx.x * 256 + threadIdx.x) >> 6;
  int lane = threadIdx.x & 63;
  int r0 = __builtin_amdgcn_readfirstlane(rowstart[node]);
  int r1 = __builtin_amdgcn_readfirstlane(rowstart[node + 1]);
  const uint2* xl2 = (const uint2*)xl;
  uint2 rp = ((const uint2*)xr)[(size_t)node * 64 + lane];
  float4 r = make_float4(bflo(rp.x), bfhi(rp.x), bflo(rp.y), bfhi(rp.y));
  float4 wv = ((const float4*)we)[lane];
  float4 at = ((const float4*)att)[lane];
  const float LOG2E = 1.442695040888963f;
  at.x *= LOG2E; at.y *= LOG2E; at.z *= LOG2E; at.w *= LOG2E;
  float4 acc = make_float4(0.f, 0.f, 0.f, 0.f);
  float denom = 0.f;

  auto edge_step = [&](float eav, uint2 p) {
    float4 a = make_float4(bflo(p.x), bfhi(p.x), bflo(p.y), bfhi(p.y));
    float s0 = a.x + (r.x + eav * wv.x);
    float s1 = a.y + (r.y + eav * wv.y);
    float s2 = a.z + (r.z + eav * wv.z);
    float s3 = a.w + (r.w + eav * wv.w);
    s0 = fmaxf(s0, 0.2f * s0);
    s1 = fmaxf(s1, 0.2f * s1);
    s2 = fmaxf(s2, 0.2f * s2);
    s3 = fmaxf(s3, 0.2f * s3);
    float p4 = (s0 * at.x + s1 * at.y) + (s2 * at.z + s3 * at.w);
#pragma unroll
    for (int off = 8; off; off >>= 1) p4 += __shfl_xor(p4, off, 16);
    float ex = exp2f(p4);
    denom += ex;
    acc.x += ex * a.x; acc.y += ex * a.y; acc.z += ex * a.z; acc.w += ex * a.w;
  };

  int i = r0;
  for (; i + 4 <= r1; i += 4) {           // 4 gathers in flight (proven schedule)
    int2 e0 = edges[i];     int2 e1 = edges[i + 1];
    int2 e2 = edges[i + 2]; int2 e3 = edges[i + 3];
    uint2 p0 = xl2[(size_t)e0.x * 64 + lane];
    uint2 p1 = xl2[(size_t)e1.x * 64 + lane];
    uint2 p2 = xl2[(size_t)e2.x * 64 + lane];
    uint2 p3 = xl2[(size_t)e3.x * 64 + lane];
    edge_step(__int_as_float(e0.y), p0);
    edge_step(__int_as_float(e1.y), p1);
    edge_step(__int_as_float(e2.y), p2);
    edge_step(__int_as_float(e3.y), p3);
  }
  for (; i < r1; ++i) {
    int2 e = edges[i];
    edge_step(__int_as_float(e.y), xl2[(size_t)e.x * 64 + lane]);
  }

  float inv = 1.f / (denom + 1e-16f);
  float4 bv = ((const float4*)bias)[lane];
  float4 o;
  o.x = fmaxf(acc.x * inv + bv.x, 0.f);
  o.y = fmaxf(acc.y * inv + bv.y, 0.f);
  o.z = fmaxf(acc.z * inv + bv.z, 0.f);
  o.w = fmaxf(acc.w * inv + bv.w, 0.f);
  uint2 pk;
  pk.x = (unsigned)f2bf(o.x) | ((unsigned)f2bf(o.y) << 16);
  pk.y = (unsigned)f2bf(o.z) | ((unsigned)f2bf(o.w) << 16);
  ((uint2*)outb)[(size_t)node * 64 + lane] = pk;
}

// ---------------- segment bounds via binary search (batch is sorted) ----------------
__global__ void seg_bounds_kernel(const int* __restrict__ batch, int* __restrict__ bounds) {
  int g = threadIdx.x;                 // 0..GG inclusive
  if (g > GG) return;
  int lo = 0, hi = NN;
  while (lo < hi) {
    int mid = (lo + hi) >> 1;
    if (batch[mid] < g) lo = mid + 1; else hi = mid;
  }
  bounds[g] = lo;
}

// ---------------- pooling (bf16 input): block = 64 nodes, 4 rg x 64 lanes ----
// Reads h as bf16 uint2 (8B/lane) — half the round-16 traffic. f32 accumulate,
// run-length per graph (batch sorted), atomicAdd flush on transition.
__global__ __launch_bounds__(256) void pool_kernel(
    const unsigned short* __restrict__ h, const int* __restrict__ batch,
    float* __restrict__ pool) {
  int rg = threadIdx.x >> 6;
  int lane = threadIdx.x & 63;
  int n0 = blockIdx.x * 64;
  const uint2* h2 = (const uint2*)h;
  float4 acc = make_float4(0.f, 0.f, 0.f, 0.f);
  int cur = -1;
#pragma unroll 4
  for (int i = 0; i < 16; ++i) {
    int n = n0 + rg + 4 * i;
    if (n >= NN) break;
    int b = batch[n];
    if (b != cur) {
      if (cur >= 0) {
        float* p = &pool[cur * 256 + lane * 4];
        atomicAdd(p + 0, acc.x); atomicAdd(p + 1, acc.y);
        atomicAdd(p + 2, acc.z); atomicAdd(p + 3, acc.w);
      }
      cur = b;
      acc = make_float4(0.f, 0.f, 0.f, 0.f);
    }
    uint2 v = h2[(size_t)n * 64 + lane];
    acc.x += bflo(v.x); acc.y += bfhi(v.x);
    acc.z += bflo(v.y); acc.w += bfhi(v.y);
  }
  if (cur >= 0) {
    float* p = &pool[cur * 256 + lane * 4];
    atomicAdd(p + 0, acc.x); atomicAdd(p + 1, acc.y);
    atomicAdd(p + 2, acc.z); atomicAdd(p + 3, acc.w);
  }
}

// ---------------- final MLP: one block (128 thr) per graph ----------------
__global__ __launch_bounds__(128) void mlp_kernel(
    const float* __restrict__ pool, const int* __restrict__ bounds,
    const float* __restrict__ p1w, const float* __restrict__ p1b,
    const float* __restrict__ lng, const float* __restrict__ lnb,
    const float* __restrict__ p2w, const float* __restrict__ p2b,
    const float* __restrict__ hw, const float* __restrict__ hb,
    float* __restrict__ out) {
  __shared__ float sg[256];
  __shared__ float red[128];
  __shared__ float sz[128];
  __shared__ float s2[64];
  int b = blockIdx.x, tid = threadIdx.x;
  float cntf = (float)(bounds[b + 1] - bounds[b]);
  float invc = 1.f / fmaxf(cntf, 1.f);
  for (int i = tid; i < 256; i += 128) sg[i] = pool[b * 256 + i] * invc;
  __syncthreads();
  float z = p1b[tid];
  for (int k = 0; k < 256; ++k) z += sg[k] * p1w[k * 128 + tid];
  red[tid] = z; __syncthreads();
  for (int off = 64; off; off >>= 1) { if (tid < off) red[tid] += red[tid + off]; __syncthreads(); }
  float mu = red[0] * (1.f / 128.f);
  __syncthreads();
  float d = z - mu;
  red[tid] = d * d; __syncthreads();
  for (int off = 64; off; off >>= 1) { if (tid < off) red[tid] += red[tid + off]; __syncthreads(); }
  float var = red[0] * (1.f / 128.f);
  float zn = d * rsqrtf(var + 1e-5f) * lng[tid] + lnb[tid];
  sz[tid] = fmaxf(zn, 0.f);
  __syncthreads();
  if (tid < 64) {
    float a = p2b[tid];
    for (int k = 0; k < 128; ++k) a += sz[k] * p2w[k * 64 + tid];
    s2[tid] = fmaxf(a, 0.f);
  }
  __syncthreads();
  if (tid < 64) {
    float p = s2[tid] * hw[tid];
    for (int off = 32; off; off >>= 1) p += __shfl_down(p, off, 64);
    if (tid == 0) out[b] = p + hb[0];
  }
}

extern "C" void kernel_launch(void* const* d_in, const int* in_sizes, int n_in,
                              void* d_out, int out_size, void* d_ws, size_t ws_size,
                              hipStream_t stream) {
  const float* x      = (const float*)d_in[0];
  const int*   ei     = (const int*)d_in[1];
  const float* ea     = (const float*)d_in[2];
  const int*   batch  = (const int*)d_in[3];
  const float* enc_w  = (const float*)d_in[4];
  const float* enc_b  = (const float*)d_in[5];
  const float* g1_wl  = (const float*)d_in[6];
  const float* g1_bl  = (const float*)d_in[7];
  const float* g1_wr  = (const float*)d_in[8];
  const float* g1_we  = (const float*)d_in[9];
  const float* g1_att = (const float*)d_in[10];
  const float* g1_b   = (const float*)d_in[11];
  const float* g2_wl  = (const float*)d_in[12];
  const float* g2_bl  = (const float*)d_in[13];
  const float* g2_wr  = (const float*)d_in[14];
  const float* g2_we  = (const float*)d_in[15];
  const float* g2_att = (const float*)d_in[16];
  const float* g2_b   = (const float*)d_in[17];
  const float* p1_w   = (const float*)d_in[18];
  const float* p1_b   = (const float*)d_in[19];
  const float* ln_g   = (const float*)d_in[20];
  const float* ln_b   = (const float*)d_in[21];
  const float* p2_w   = (const float*)d_in[22];
  const float* p2_b   = (const float*)d_in[23];
  const float* head_w = (const float*)d_in[24];
  const float* head_b = (const float*)d_in[25];
  float* out = (float*)d_out;

  char* ws = (char*)d_ws;
  size_t off = 0;
  auto alloc = [&](size_t bytes) -> void* {
    void* p = ws + off;
    off = (off + bytes + 255) & ~(size_t)255;
    return p;
  };
  unsigned short* xl   = (unsigned short*)alloc((size_t)NN * HC * 2);
  unsigned short* xr   = (unsigned short*)alloc((size_t)NN * HC * 2);
  unsigned short* h0   = (unsigned short*)alloc((size_t)NN * 64 * 2);
  unsigned short* hb16 = (unsigned short*)alloc((size_t)NN * HC * 2);
  unsigned short* wt1  = (unsigned short*)alloc((size_t)512 * 64 * 2);
  unsigned short* wt2  = (unsigned short*)alloc((size_t)512 * 256 * 2);
  float* pool      = (float*)alloc((size_t)GG * HC * 4);
  int*   deg       = (int*)alloc((size_t)NN * 4);
  int*   rowstart  = (int*)alloc((size_t)(NN + 1) * 4);
  int*   cursor    = (int*)alloc((size_t)NN * 4);
  int*   bsum      = (int*)alloc((size_t)NB * 4);
  int*   bpre      = (int*)alloc((size_t)NB * 4);
  int2*  edges     = (int2*)alloc((size_t)NE * 8);
  int*   bounds    = (int*)alloc((size_t)(GG + 1) * 4);

  hipMemsetAsync(deg, 0, (size_t)NN * 4, stream);
  hipMemsetAsync(pool, 0, (size_t)GG * HC * 4, stream);

  // encoder (bf16 out) + weight prep (concatenated [512][K] layouts)
  encoder_kernel<<<NN * 64 / 256, 256, 0, stream>>>(x, enc_w, enc_b, h0);
  wconv_kernel<<<64, 256, 0, stream>>>(g1_wl, 64, wt1);
  wconv_kernel<<<64, 256, 0, stream>>>(g1_wr, 64, wt1 + (size_t)256 * 64);
  wconv_kernel<<<256, 256, 0, stream>>>(g2_wl, 256, wt2);
  wconv_kernel<<<256, 256, 0, stream>>>(g2_wr, 256, wt2 + (size_t)256 * 256);

  // CSR build: degree -> hierarchical scan -> fill
  degree_kernel<<<(NE + 255) / 256, 256, 0, stream>>>(ei, deg);
  blocksum_kernel<<<NB, 256, 0, stream>>>(deg, bsum);
  blockscan_kernel<<<1, 256, 0, stream>>>(bsum, bpre, rowstart);
  rowstart_kernel<<<NB, 256, 0, stream>>>(deg, bpre, rowstart, cursor);
  fill_kernel<<<(NE + 255) / 256, 256, 0, stream>>>(ei, ea, cursor, edges);

  // graph segment bounds (batch is sorted)
  seg_bounds_kernel<<<1, GG + 1, 0, stream>>>(batch, bounds);

  dim3 mmg((NN + 127) / 128, 4);   // 391 x 4 blocks over the 512 concat cols

  // ---- GAT layer 1 (K=64): one matmul launch -> xl/xr, then edge phase ----
  matmul_mfma_kernel<64><<<mmg, 256, 0, stream>>>(h0, wt1, g1_bl, xl, xr, NN);
  gat_fused_kernel<<<NN / 4, 256, 0, stream>>>(rowstart, edges, xl, xr,
                                               g1_we, g1_att, g1_b, hb16);

  // ---- GAT layer 2 (K=256): matmul, then edge phase (bf16 out -> pooling) ----
  matmul_mfma_kernel<256><<<mmg, 256, 0, stream>>>(hb16, wt2, g2_bl, xl, xr, NN);
  gat_fused_kernel<<<NN / 4, 256, 0, stream>>>(rowstart, edges, xl, xr,
                                               g2_we, g2_att, g2_b, hb16);

  // ---- pooling (bf16 in) + MLP head ----
  pool_kernel<<<(NN + 63) / 64, 256, 0, stream>>>(hb16, batch, pool);
  mlp_kernel<<<GG, 128, 0, stream>>>(pool, bounds, p1_w, p1_b, ln_g, ln_b,
                                     p2_w, p2_b, head_w, head_b, out);
}

// Round 20
// 347.285 us; speedup vs baseline: 1.1332x; 1.0848x over previous
//
#include <hip/hip_runtime.h>
#include <hip/hip_bf16.h>
#include <math.h>

#define NN 50000     // nodes
#define NE 400000    // edges
#define HH 4         // heads
#define CC 64        // per-head dim
#define HC 256       // H*C
#define GG 64        // graphs
#define NB 196       // scan blocks: ceil(NN/256)

typedef short v8s __attribute__((ext_vector_type(8)));
typedef float f32x4 __attribute__((ext_vector_type(4)));

static __device__ inline unsigned short f2bf(float v) {
  __hip_bfloat16 b = __float2bfloat16(v);
  return *reinterpret_cast<unsigned short*>(&b);
}
// packed bf16 pair -> f32 (bf16 value = bit pattern << 16)
static __device__ inline float bflo(unsigned u) { return __uint_as_float(u << 16); }
static __device__ inline float bfhi(unsigned u) { return __uint_as_float(u & 0xffff0000u); }

// ---------------- encoder: h0 = relu(x @ enc_w + enc_b) -> bf16 ----------------
__global__ __launch_bounds__(256) void encoder_kernel(
    const float* __restrict__ x, const float* __restrict__ w,
    const float* __restrict__ b, unsigned short* __restrict__ h0) {
  int idx = blockIdx.x * 256 + threadIdx.x;   // N*64 threads
  int node = idx >> 6, col = idx & 63;
  const float* xr = x + node * 8;
  float acc = b[col];
#pragma unroll
  for (int k = 0; k < 8; ++k) acc += xr[k] * w[k * 64 + col];
  h0[idx] = f2bf(fmaxf(acc, 0.f));
}

// ---- W prep: W[K,256] f32 -> Wt bf16 [256][K] (k-contiguous rows) ----
__global__ __launch_bounds__(256) void wconv_kernel(
    const float* __restrict__ W, int K, unsigned short* __restrict__ Wt) {
  int idx = blockIdx.x * 256 + threadIdx.x;
  if (idx >= K * 256) return;
  int k = idx >> 8, n = idx & 255;
  Wt[n * K + k] = f2bf(W[idx]);
}

// ------- MFMA matmul: {xl,xr}(bf16)[M,256] = A(bf16) @ [Wl;Wr] (bias on xl) -------
// Wcat = [512][K] k-contiguous rows. Block 128 rows x 128 cols, blockIdx.y 0..3.
// Epilogue routes C through LDS: the old per-element 2B scatter stores made the
// kernel HBM-bound at 2 TB/s (write-allocate partial lines; FETCH 54MB even at
// K=64). Now: bf16 pack -> LDS stage (32x136-short, bank-spread) -> 256B-coalesced
// uint4 row stores.
template <int K>
__global__ __launch_bounds__(256) void matmul_mfma_kernel(
    const unsigned short* __restrict__ A, const unsigned short* __restrict__ Wt,
    const float* __restrict__ bias,
    unsigned short* __restrict__ outL, unsigned short* __restrict__ outR, int M) {
  constexpr int AP = 40;                 // LDS k-stride (shorts): 80B, 16B-aligned
  __shared__ unsigned short a_lds[128 * AP];   // 10240 B (also reused as C stage)
  __shared__ unsigned short b_lds[128 * AP];
  const int tid = threadIdx.x;
  const int wave = tid >> 6;
  const int lane = tid & 63;
  const int quad = lane >> 4;
  const int lrow = lane & 15;
  const int wr = (wave & 1) * 64;
  const int wc = (wave >> 1) * 64;
  const int r0 = blockIdx.x * 128;
  const int n0 = blockIdx.y * 128;       // 0..384 over the 512 concat cols

  f32x4 acc[4][4];
#pragma unroll
  for (int i = 0; i < 4; ++i)
#pragma unroll
    for (int j = 0; j < 4; ++j) acc[i][j] = (f32x4){0.f, 0.f, 0.f, 0.f};

  const int srow = tid >> 1;
  const int shalf = tid & 1;
  int agrow = r0 + srow; if (agrow >= M) agrow = M - 1;   // clamp; stores guarded
  const int bgrow = n0 + srow;

  for (int k0 = 0; k0 < K; k0 += 32) {
    {
      const float4* sa = (const float4*)&A[(size_t)agrow * K + k0 + shalf * 16];
      const float4* sb = (const float4*)&Wt[(size_t)bgrow * K + k0 + shalf * 16];
      float4 va0 = sa[0], va1 = sa[1];
      float4 vb0 = sb[0], vb1 = sb[1];
      *(float4*)&a_lds[srow * AP + shalf * 16]     = va0;
      *(float4*)&a_lds[srow * AP + shalf * 16 + 8] = va1;
      *(float4*)&b_lds[srow * AP + shalf * 16]     = vb0;
      *(float4*)&b_lds[srow * AP + shalf * 16 + 8] = vb1;
    }
    __syncthreads();

    v8s af[4], bf[4];
#pragma unroll
    for (int rt = 0; rt < 4; ++rt)
      af[rt] = *(const v8s*)&a_lds[(wr + rt * 16 + lrow) * AP + quad * 8];
#pragma unroll
    for (int ct = 0; ct < 4; ++ct)
      bf[ct] = *(const v8s*)&b_lds[(wc + ct * 16 + lrow) * AP + quad * 8];
#pragma unroll
    for (int rt = 0; rt < 4; ++rt)
#pragma unroll
      for (int ct = 0; ct < 4; ++ct)
        acc[rt][ct] = __builtin_amdgcn_mfma_f32_16x16x32_bf16(af[rt], bf[ct], acc[rt][ct], 0, 0, 0);
    __syncthreads();
  }

  const bool isL = (n0 < 256);
  unsigned short* outp = isL ? outL : outR;
  const int cbase = isL ? n0 : (n0 - 256);
  constexpr int SP = 136;                // stage row stride (272B: 16B-mult, bank-spread)
  unsigned short* stage = a_lds;         // 32*136*2 = 8704B <= 10240B

#pragma unroll
  for (int rt = 0; rt < 4; ++rt) {
    __syncthreads();                     // stage free (prev rt reads / k-loop done)
#pragma unroll
    for (int ct = 0; ct < 4; ++ct) {
      int col = wc + ct * 16 + lrow;     // 0..127 within block
      float b = isL ? bias[cbase + col] : 0.f;
#pragma unroll
      for (int r = 0; r < 4; ++r) {
        int sr = (wave & 1) * 16 + quad * 4 + r;   // 0..31
        stage[sr * SP + col] = f2bf(acc[rt][ct][r] + b);
      }
    }
    __syncthreads();
    int sr = tid >> 3;                   // 0..31
    int c0 = (tid & 7) * 16;             // shorts; 8 threads cover 128 cols
    int grow = r0 + (sr >> 4) * 64 + rt * 16 + (sr & 15);
    if (grow < M) {
      uint4 v0 = *(const uint4*)&stage[sr * SP + c0];
      uint4 v1 = *(const uint4*)&stage[sr * SP + c0 + 8];
      *(uint4*)&outp[(size_t)grow * 256 + cbase + c0] = v0;
      *(uint4*)&outp[(size_t)grow * 256 + cbase + c0 + 8] = v1;
    }
  }
}

// ---------------- CSR build ----------------
__global__ void degree_kernel(const int* __restrict__ ei, int* __restrict__ deg) {
  int e = blockIdx.x * 256 + threadIdx.x;
  if (e < NE) atomicAdd(&deg[ei[NE + e]], 1);
}

__global__ __launch_bounds__(256) void blocksum_kernel(
    const int* __restrict__ deg, int* __restrict__ bsum) {
  int t = threadIdx.x;
  int i = blockIdx.x * 256 + t;
  int v = (i < NN) ? deg[i] : 0;
#pragma unroll
  for (int off = 32; off; off >>= 1) v += __shfl_down(v, off, 64);
  __shared__ int ws[4];
  if ((t & 63) == 0) ws[t >> 6] = v;
  __syncthreads();
  if (t == 0) bsum[blockIdx.x] = ws[0] + ws[1] + ws[2] + ws[3];
}

__global__ __launch_bounds__(256) void blockscan_kernel(
    const int* __restrict__ bsum, int* __restrict__ bpre, int* __restrict__ rowstart) {
  __shared__ int s[256];
  int t = threadIdx.x;
  int v = (t < NB) ? bsum[t] : 0;
  s[t] = v;
  __syncthreads();
  for (int off = 1; off < 256; off <<= 1) {
    int x = s[t];
    int y = (t >= off) ? s[t - off] : 0;
    __syncthreads();
    s[t] = x + y;
    __syncthreads();
  }
  if (t < NB) bpre[t] = s[t] - v;
  if (t == 255) rowstart[NN] = s[255];
}

__global__ __launch_bounds__(256) void rowstart_kernel(
    const int* __restrict__ deg, const int* __restrict__ bpre,
    int* __restrict__ rowstart, int* __restrict__ cursor) {
  __shared__ int s[256];
  int t = threadIdx.x;
  int i = blockIdx.x * 256 + t;
  int v = (i < NN) ? deg[i] : 0;
  s[t] = v;
  __syncthreads();
  for (int off = 1; off < 256; off <<= 1) {
    int x = s[t];
    int y = (t >= off) ? s[t - off] : 0;
    __syncthreads();
    s[t] = x + y;
    __syncthreads();
  }
  if (i < NN) {
    int rs = bpre[blockIdx.x] + s[t] - v;
    rowstart[i] = rs;
    cursor[i] = rs;
  }
}

// CSR fill: single int2 (src, ea-bits) per edge -> one aligned 8B scatter store.
__global__ void fill_kernel(const int* __restrict__ ei, const float* __restrict__ ea,
                            int* __restrict__ cursor, int2* __restrict__ edges) {
  int e = blockIdx.x * 256 + threadIdx.x;
  if (e < NE) {
    int d = ei[NE + e];
    int pos = atomicAdd(&cursor[d], 1);
    edges[pos] = make_int2(ei[e], __float_as_int(ea[e]));
  }
}

// ---------------- fused GATv2 edge phase: wave per dst node (round-16 body) ----
__global__ __launch_bounds__(256) void gat_fused_kernel(
    const int* __restrict__ rowstart, const int2* __restrict__ edges,
    const unsigned short* __restrict__ xl, const unsigned short* __restrict__ xr,
    const float* __restrict__ we, const float* __restrict__ att,
    const float* __restrict__ bias, unsigned short* __restrict__ outb) {
  int node = (blockIdx.x * 256 + threadIdx.x) >> 6;
  int lane = threadIdx.x & 63;
  int r0 = __builtin_amdgcn_readfirstlane(rowstart[node]);
  int r1 = __builtin_amdgcn_readfirstlane(rowstart[node + 1]);
  const uint2* xl2 = (const uint2*)xl;
  uint2 rp = ((const uint2*)xr)[(size_t)node * 64 + lane];
  float4 r = make_float4(bflo(rp.x), bfhi(rp.x), bflo(rp.y), bfhi(rp.y));
  float4 wv = ((const float4*)we)[lane];
  float4 at = ((const float4*)att)[lane];
  const float LOG2E = 1.442695040888963f;
  at.x *= LOG2E; at.y *= LOG2E; at.z *= LOG2E; at.w *= LOG2E;
  float4 acc = make_float4(0.f, 0.f, 0.f, 0.f);
  float denom = 0.f;

  auto edge_step = [&](float eav, uint2 p) {
    float4 a = make_float4(bflo(p.x), bfhi(p.x), bflo(p.y), bfhi(p.y));
    float s0 = a.x + (r.x + eav * wv.x);
    float s1 = a.y + (r.y + eav * wv.y);
    float s2 = a.z + (r.z + eav * wv.z);
    float s3 = a.w + (r.w + eav * wv.w);
    s0 = fmaxf(s0, 0.2f * s0);
    s1 = fmaxf(s1, 0.2f * s1);
    s2 = fmaxf(s2, 0.2f * s2);
    s3 = fmaxf(s3, 0.2f * s3);
    float p4 = (s0 * at.x + s1 * at.y) + (s2 * at.z + s3 * at.w);
#pragma unroll
    for (int off = 8; off; off >>= 1) p4 += __shfl_xor(p4, off, 16);
    float ex = exp2f(p4);
    denom += ex;
    acc.x += ex * a.x; acc.y += ex * a.y; acc.z += ex * a.z; acc.w += ex * a.w;
  };

  int i = r0;
  for (; i + 4 <= r1; i += 4) {           // 4 gathers in flight (proven schedule)
    int2 e0 = edges[i];     int2 e1 = edges[i + 1];
    int2 e2 = edges[i + 2]; int2 e3 = edges[i + 3];
    uint2 p0 = xl2[(size_t)e0.x * 64 + lane];
    uint2 p1 = xl2[(size_t)e1.x * 64 + lane];
    uint2 p2 = xl2[(size_t)e2.x * 64 + lane];
    uint2 p3 = xl2[(size_t)e3.x * 64 + lane];
    edge_step(__int_as_float(e0.y), p0);
    edge_step(__int_as_float(e1.y), p1);
    edge_step(__int_as_float(e2.y), p2);
    edge_step(__int_as_float(e3.y), p3);
  }
  for (; i < r1; ++i) {
    int2 e = edges[i];
    edge_step(__int_as_float(e.y), xl2[(size_t)e.x * 64 + lane]);
  }

  float inv = 1.f / (denom + 1e-16f);
  float4 bv = ((const float4*)bias)[lane];
  float4 o;
  o.x = fmaxf(acc.x * inv + bv.x, 0.f);
  o.y = fmaxf(acc.y * inv + bv.y, 0.f);
  o.z = fmaxf(acc.z * inv + bv.z, 0.f);
  o.w = fmaxf(acc.w * inv + bv.w, 0.f);
  uint2 pk;
  pk.x = (unsigned)f2bf(o.x) | ((unsigned)f2bf(o.y) << 16);
  pk.y = (unsigned)f2bf(o.z) | ((unsigned)f2bf(o.w) << 16);
  ((uint2*)outb)[(size_t)node * 64 + lane] = pk;
}

// ---------------- segment bounds via binary search (batch is sorted) ----------------
__global__ void seg_bounds_kernel(const int* __restrict__ batch, int* __restrict__ bounds) {
  int g = threadIdx.x;                 // 0..GG inclusive
  if (g > GG) return;
  int lo = 0, hi = NN;
  while (lo < hi) {
    int mid = (lo + hi) >> 1;
    if (batch[mid] < g) lo = mid + 1; else hi = mid;
  }
  bounds[g] = lo;
}

// ---------------- pooling (bf16 input): block = 64 nodes, 4 rg x 64 lanes ----
__global__ __launch_bounds__(256) void pool_kernel(
    const unsigned short* __restrict__ h, const int* __restrict__ batch,
    float* __restrict__ pool) {
  int rg = threadIdx.x >> 6;
  int lane = threadIdx.x & 63;
  int n0 = blockIdx.x * 64;
  const uint2* h2 = (const uint2*)h;
  float4 acc = make_float4(0.f, 0.f, 0.f, 0.f);
  int cur = -1;
#pragma unroll 4
  for (int i = 0; i < 16; ++i) {
    int n = n0 + rg + 4 * i;
    if (n >= NN) break;
    int b = batch[n];
    if (b != cur) {
      if (cur >= 0) {
        float* p = &pool[cur * 256 + lane * 4];
        atomicAdd(p + 0, acc.x); atomicAdd(p + 1, acc.y);
        atomicAdd(p + 2, acc.z); atomicAdd(p + 3, acc.w);
      }
      cur = b;
      acc = make_float4(0.f, 0.f, 0.f, 0.f);
    }
    uint2 v = h2[(size_t)n * 64 + lane];
    acc.x += bflo(v.x); acc.y += bfhi(v.x);
    acc.z += bflo(v.y); acc.w += bfhi(v.y);
  }
  if (cur >= 0) {
    float* p = &pool[cur * 256 + lane * 4];
    atomicAdd(p + 0, acc.x); atomicAdd(p + 1, acc.y);
    atomicAdd(p + 2, acc.z); atomicAdd(p + 3, acc.w);
  }
}

// ---------------- final MLP: one block (128 thr) per graph ----------------
__global__ __launch_bounds__(128) void mlp_kernel(
    const float* __restrict__ pool, const int* __restrict__ bounds,
    const float* __restrict__ p1w, const float* __restrict__ p1b,
    const float* __restrict__ lng, const float* __restrict__ lnb,
    const float* __restrict__ p2w, const float* __restrict__ p2b,
    const float* __restrict__ hw, const float* __restrict__ hb,
    float* __restrict__ out) {
  __shared__ float sg[256];
  __shared__ float red[128];
  __shared__ float sz[128];
  __shared__ float s2[64];
  int b = blockIdx.x, tid = threadIdx.x;
  float cntf = (float)(bounds[b + 1] - bounds[b]);
  float invc = 1.f / fmaxf(cntf, 1.f);
  for (int i = tid; i < 256; i += 128) sg[i] = pool[b * 256 + i] * invc;
  __syncthreads();
  float z = p1b[tid];
  for (int k = 0; k < 256; ++k) z += sg[k] * p1w[k * 128 + tid];
  red[tid] = z; __syncthreads();
  for (int off = 64; off; off >>= 1) { if (tid < off) red[tid] += red[tid + off]; __syncthreads(); }
  float mu = red[0] * (1.f / 128.f);
  __syncthreads();
  float d = z - mu;
  red[tid] = d * d; __syncthreads();
  for (int off = 64; off; off >>= 1) { if (tid < off) red[tid] += red[tid + off]; __syncthreads(); }
  float var = red[0] * (1.f / 128.f);
  float zn = d * rsqrtf(var + 1e-5f) * lng[tid] + lnb[tid];
  sz[tid] = fmaxf(zn, 0.f);
  __syncthreads();
  if (tid < 64) {
    float a = p2b[tid];
    for (int k = 0; k < 128; ++k) a += sz[k] * p2w[k * 64 + tid];
    s2[tid] = fmaxf(a, 0.f);
  }
  __syncthreads();
  if (tid < 64) {
    float p = s2[tid] * hw[tid];
    for (int off = 32; off; off >>= 1) p += __shfl_down(p, off, 64);
    if (tid == 0) out[b] = p + hb[0];
  }
}

extern "C" void kernel_launch(void* const* d_in, const int* in_sizes, int n_in,
                              void* d_out, int out_size, void* d_ws, size_t ws_size,
                              hipStream_t stream) {
  const float* x      = (const float*)d_in[0];
  const int*   ei     = (const int*)d_in[1];
  const float* ea     = (const float*)d_in[2];
  const int*   batch  = (const int*)d_in[3];
  const float* enc_w  = (const float*)d_in[4];
  const float* enc_b  = (const float*)d_in[5];
  const float* g1_wl  = (const float*)d_in[6];
  const float* g1_bl  = (const float*)d_in[7];
  const float* g1_wr  = (const float*)d_in[8];
  const float* g1_we  = (const float*)d_in[9];
  const float* g1_att = (const float*)d_in[10];
  const float* g1_b   = (const float*)d_in[11];
  const float* g2_wl  = (const float*)d_in[12];
  const float* g2_bl  = (const float*)d_in[13];
  const float* g2_wr  = (const float*)d_in[14];
  const float* g2_we  = (const float*)d_in[15];
  const float* g2_att = (const float*)d_in[16];
  const float* g2_b   = (const float*)d_in[17];
  const float* p1_w   = (const float*)d_in[18];
  const float* p1_b   = (const float*)d_in[19];
  const float* ln_g   = (const float*)d_in[20];
  const float* ln_b   = (const float*)d_in[21];
  const float* p2_w   = (const float*)d_in[22];
  const float* p2_b   = (const float*)d_in[23];
  const float* head_w = (const float*)d_in[24];
  const float* head_b = (const float*)d_in[25];
  float* out = (float*)d_out;

  char* ws = (char*)d_ws;
  size_t off = 0;
  auto alloc = [&](size_t bytes) -> void* {
    void* p = ws + off;
    off = (off + bytes + 255) & ~(size_t)255;
    return p;
  };
  unsigned short* xl   = (unsigned short*)alloc((size_t)NN * HC * 2);
  unsigned short* xr   = (unsigned short*)alloc((size_t)NN * HC * 2);
  unsigned short* h0   = (unsigned short*)alloc((size_t)NN * 64 * 2);
  unsigned short* hb16 = (unsigned short*)alloc((size_t)NN * HC * 2);
  unsigned short* wt1  = (unsigned short*)alloc((size_t)512 * 64 * 2);
  unsigned short* wt2  = (unsigned short*)alloc((size_t)512 * 256 * 2);
  float* pool      = (float*)alloc((size_t)GG * HC * 4);
  int*   deg       = (int*)alloc((size_t)NN * 4);
  int*   rowstart  = (int*)alloc((size_t)(NN + 1) * 4);
  int*   cursor    = (int*)alloc((size_t)NN * 4);
  int*   bsum      = (int*)alloc((size_t)NB * 4);
  int*   bpre      = (int*)alloc((size_t)NB * 4);
  int2*  edges     = (int2*)alloc((size_t)NE * 8);
  int*   bounds    = (int*)alloc((size_t)(GG + 1) * 4);

  hipMemsetAsync(deg, 0, (size_t)NN * 4, stream);
  hipMemsetAsync(pool, 0, (size_t)GG * HC * 4, stream);

  // encoder (bf16 out) + weight prep (concatenated [512][K] layouts)
  encoder_kernel<<<NN * 64 / 256, 256, 0, stream>>>(x, enc_w, enc_b, h0);
  wconv_kernel<<<64, 256, 0, stream>>>(g1_wl, 64, wt1);
  wconv_kernel<<<64, 256, 0, stream>>>(g1_wr, 64, wt1 + (size_t)256 * 64);
  wconv_kernel<<<256, 256, 0, stream>>>(g2_wl, 256, wt2);
  wconv_kernel<<<256, 256, 0, stream>>>(g2_wr, 256, wt2 + (size_t)256 * 256);

  // CSR build: degree -> hierarchical scan -> fill
  degree_kernel<<<(NE + 255) / 256, 256, 0, stream>>>(ei, deg);
  blocksum_kernel<<<NB, 256, 0, stream>>>(deg, bsum);
  blockscan_kernel<<<1, 256, 0, stream>>>(bsum, bpre, rowstart);
  rowstart_kernel<<<NB, 256, 0, stream>>>(deg, bpre, rowstart, cursor);
  fill_kernel<<<(NE + 255) / 256, 256, 0, stream>>>(ei, ea, cursor, edges);

  // graph segment bounds (batch is sorted)
  seg_bounds_kernel<<<1, GG + 1, 0, stream>>>(batch, bounds);

  dim3 mmg((NN + 127) / 128, 4);   // 391 x 4 blocks over the 512 concat cols

  // ---- GAT layer 1 (K=64): one matmul launch -> xl/xr, then edge phase ----
  matmul_mfma_kernel<64><<<mmg, 256, 0, stream>>>(h0, wt1, g1_bl, xl, xr, NN);
  gat_fused_kernel<<<NN / 4, 256, 0, stream>>>(rowstart, edges, xl, xr,
                                               g1_we, g1_att, g1_b, hb16);

  // ---- GAT layer 2 (K=256): matmul, then edge phase (bf16 out -> pooling) ----
  matmul_mfma_kernel<256><<<mmg, 256, 0, stream>>>(hb16, wt2, g2_bl, xl, xr, NN);
  gat_fused_kernel<<<NN / 4, 256, 0, stream>>>(rowstart, edges, xl, xr,
                                               g2_we, g2_att, g2_b, hb16);

  // ---- pooling (bf16 in) + MLP head ----
  pool_kernel<<<(NN + 63) / 64, 256, 0, stream>>>(hb16, batch, pool);
  mlp_kernel<<<GG, 128, 0, stream>>>(pool, bounds, p1_w, p1_b, ln_g, ln_b,
                                     p2_w, p2_b, head_w, head_b, out);
}

// Round 21
// 341.926 us; speedup vs baseline: 1.1510x; 1.0157x over previous
//
#include <hip/hip_runtime.h>
#include <hip/hip_bf16.h>
#include <math.h>

#define NN 50000     // nodes
#define NE 400000    // edges
#define HH 4         // heads
#define CC 64        // per-head dim
#define HC 256       // H*C
#define GG 64        // graphs
#define NB 196       // scan blocks: ceil(NN/256)

typedef short v8s __attribute__((ext_vector_type(8)));
typedef float f32x4 __attribute__((ext_vector_type(4)));

static __device__ inline unsigned short f2bf(float v) {
  __hip_bfloat16 b = __float2bfloat16(v);
  return *reinterpret_cast<unsigned short*>(&b);
}
// packed bf16 pair -> f32 (bf16 value = bit pattern << 16)
static __device__ inline float bflo(unsigned u) { return __uint_as_float(u << 16); }
static __device__ inline float bfhi(unsigned u) { return __uint_as_float(u & 0xffff0000u); }

// ---------------- encoder: h0 = relu(x @ enc_w + enc_b) -> bf16 ----------------
__global__ __launch_bounds__(256) void encoder_kernel(
    const float* __restrict__ x, const float* __restrict__ w,
    const float* __restrict__ b, unsigned short* __restrict__ h0) {
  int idx = blockIdx.x * 256 + threadIdx.x;   // N*64 threads
  int node = idx >> 6, col = idx & 63;
  const float* xr = x + node * 8;
  float acc = b[col];
#pragma unroll
  for (int k = 0; k < 8; ++k) acc += xr[k] * w[k * 64 + col];
  h0[idx] = f2bf(fmaxf(acc, 0.f));
}

// ---- all 4 W preps in ONE launch: W[K,256] f32 -> Wt bf16 [256][K] rows ----
// regions: [0,16384) g1_wl  [16384,32768) g1_wr  [32768,98304) g2_wl  [98304,163840) g2_wr
__global__ __launch_bounds__(256) void wconv_all_kernel(
    const float* __restrict__ g1_wl, const float* __restrict__ g1_wr,
    const float* __restrict__ g2_wl, const float* __restrict__ g2_wr,
    unsigned short* __restrict__ wt1, unsigned short* __restrict__ wt2) {
  int idx = blockIdx.x * 256 + threadIdx.x;
  const float* W; unsigned short* Wt; int K; int base;
  if (idx < 16384)        { W = g1_wl; Wt = wt1;                     K = 64;  base = idx; }
  else if (idx < 32768)   { W = g1_wr; Wt = wt1 + (size_t)256 * 64;  K = 64;  base = idx - 16384; }
  else if (idx < 98304)   { W = g2_wl; Wt = wt2;                     K = 256; base = idx - 32768; }
  else if (idx < 163840)  { W = g2_wr; Wt = wt2 + (size_t)256 * 256; K = 256; base = idx - 98304; }
  else return;
  int k = base >> 8, n = base & 255;
  Wt[n * K + k] = f2bf(W[base]);
}

// ---- setup: zero deg + zero pool + graph segment bounds (batch sorted) ----
__global__ __launch_bounds__(256) void setup_kernel(
    const int* __restrict__ batch, int* __restrict__ deg,
    float* __restrict__ pool, int* __restrict__ bounds) {
  int bid = blockIdx.x, tid = threadIdx.x;
  int i = bid * 256 + tid;
  if (i < NN) deg[i] = 0;
  if (bid < GG) pool[bid * 256 + tid] = 0.f;
  if (bid == NB - 1 && tid <= GG) {
    int g = tid, lo = 0, hi = NN;
    while (lo < hi) {
      int mid = (lo + hi) >> 1;
      if (batch[mid] < g) lo = mid + 1; else hi = mid;
    }
    bounds[g] = lo;
  }
}

// ------- MFMA matmul: {xl,xr}(bf16)[M,256] = A(bf16) @ [Wl;Wr] (bias on xl) -------
// Wcat = [512][K] k-contiguous rows. Block 128 rows x 128 cols, blockIdx.y 0..3.
// Epilogue routes C through LDS (bf16 pack -> 32x136-short stage -> 256B-coalesced
// uint4 row stores) — per-element 2B scatter stores were write-allocate bound.
template <int K>
__global__ __launch_bounds__(256) void matmul_mfma_kernel(
    const unsigned short* __restrict__ A, const unsigned short* __restrict__ Wt,
    const float* __restrict__ bias,
    unsigned short* __restrict__ outL, unsigned short* __restrict__ outR, int M) {
  constexpr int AP = 40;                 // LDS k-stride (shorts): 80B, 16B-aligned
  __shared__ unsigned short a_lds[128 * AP];   // 10240 B (also reused as C stage)
  __shared__ unsigned short b_lds[128 * AP];
  const int tid = threadIdx.x;
  const int wave = tid >> 6;
  const int lane = tid & 63;
  const int quad = lane >> 4;
  const int lrow = lane & 15;
  const int wr = (wave & 1) * 64;
  const int wc = (wave >> 1) * 64;
  const int r0 = blockIdx.x * 128;
  const int n0 = blockIdx.y * 128;       // 0..384 over the 512 concat cols

  f32x4 acc[4][4];
#pragma unroll
  for (int i = 0; i < 4; ++i)
#pragma unroll
    for (int j = 0; j < 4; ++j) acc[i][j] = (f32x4){0.f, 0.f, 0.f, 0.f};

  const int srow = tid >> 1;
  const int shalf = tid & 1;
  int agrow = r0 + srow; if (agrow >= M) agrow = M - 1;   // clamp; stores guarded
  const int bgrow = n0 + srow;

  for (int k0 = 0; k0 < K; k0 += 32) {
    {
      const float4* sa = (const float4*)&A[(size_t)agrow * K + k0 + shalf * 16];
      const float4* sb = (const float4*)&Wt[(size_t)bgrow * K + k0 + shalf * 16];
      float4 va0 = sa[0], va1 = sa[1];
      float4 vb0 = sb[0], vb1 = sb[1];
      *(float4*)&a_lds[srow * AP + shalf * 16]     = va0;
      *(float4*)&a_lds[srow * AP + shalf * 16 + 8] = va1;
      *(float4*)&b_lds[srow * AP + shalf * 16]     = vb0;
      *(float4*)&b_lds[srow * AP + shalf * 16 + 8] = vb1;
    }
    __syncthreads();

    v8s af[4], bf[4];
#pragma unroll
    for (int rt = 0; rt < 4; ++rt)
      af[rt] = *(const v8s*)&a_lds[(wr + rt * 16 + lrow) * AP + quad * 8];
#pragma unroll
    for (int ct = 0; ct < 4; ++ct)
      bf[ct] = *(const v8s*)&b_lds[(wc + ct * 16 + lrow) * AP + quad * 8];
#pragma unroll
    for (int rt = 0; rt < 4; ++rt)
#pragma unroll
      for (int ct = 0; ct < 4; ++ct)
        acc[rt][ct] = __builtin_amdgcn_mfma_f32_16x16x32_bf16(af[rt], bf[ct], acc[rt][ct], 0, 0, 0);
    __syncthreads();
  }

  const bool isL = (n0 < 256);
  unsigned short* outp = isL ? outL : outR;
  const int cbase = isL ? n0 : (n0 - 256);
  constexpr int SP = 136;                // stage row stride (272B: 16B-mult, bank-spread)
  unsigned short* stage = a_lds;         // 32*136*2 = 8704B <= 10240B

#pragma unroll
  for (int rt = 0; rt < 4; ++rt) {
    __syncthreads();                     // stage free (prev rt reads / k-loop done)
#pragma unroll
    for (int ct = 0; ct < 4; ++ct) {
      int col = wc + ct * 16 + lrow;     // 0..127 within block
      float b = isL ? bias[cbase + col] : 0.f;
#pragma unroll
      for (int r = 0; r < 4; ++r) {
        int sr = (wave & 1) * 16 + quad * 4 + r;   // 0..31
        stage[sr * SP + col] = f2bf(acc[rt][ct][r] + b);
      }
    }
    __syncthreads();
    int sr = tid >> 3;                   // 0..31
    int c0 = (tid & 7) * 16;             // shorts; 8 threads cover 128 cols
    int grow = r0 + (sr >> 4) * 64 + rt * 16 + (sr & 15);
    if (grow < M) {
      uint4 v0 = *(const uint4*)&stage[sr * SP + c0];
      uint4 v1 = *(const uint4*)&stage[sr * SP + c0 + 8];
      *(uint4*)&outp[(size_t)grow * 256 + cbase + c0] = v0;
      *(uint4*)&outp[(size_t)grow * 256 + cbase + c0 + 8] = v1;
    }
  }
}

// ---------------- CSR build ----------------
__global__ void degree_kernel(const int* __restrict__ ei, int* __restrict__ deg) {
  int e = blockIdx.x * 256 + threadIdx.x;
  if (e < NE) atomicAdd(&deg[ei[NE + e]], 1);
}

__global__ __launch_bounds__(256) void blocksum_kernel(
    const int* __restrict__ deg, int* __restrict__ bsum) {
  int t = threadIdx.x;
  int i = blockIdx.x * 256 + t;
  int v = (i < NN) ? deg[i] : 0;
#pragma unroll
  for (int off = 32; off; off >>= 1) v += __shfl_down(v, off, 64);
  __shared__ int ws[4];
  if ((t & 63) == 0) ws[t >> 6] = v;
  __syncthreads();
  if (t == 0) bsum[blockIdx.x] = ws[0] + ws[1] + ws[2] + ws[3];
}

__global__ __launch_bounds__(256) void blockscan_kernel(
    const int* __restrict__ bsum, int* __restrict__ bpre, int* __restrict__ rowstart) {
  __shared__ int s[256];
  int t = threadIdx.x;
  int v = (t < NB) ? bsum[t] : 0;
  s[t] = v;
  __syncthreads();
  for (int off = 1; off < 256; off <<= 1) {
    int x = s[t];
    int y = (t >= off) ? s[t - off] : 0;
    __syncthreads();
    s[t] = x + y;
    __syncthreads();
  }
  if (t < NB) bpre[t] = s[t] - v;
  if (t == 255) rowstart[NN] = s[255];
}

__global__ __launch_bounds__(256) void rowstart_kernel(
    const int* __restrict__ deg, const int* __restrict__ bpre,
    int* __restrict__ rowstart, int* __restrict__ cursor) {
  __shared__ int s[256];
  int t = threadIdx.x;
  int i = blockIdx.x * 256 + t;
  int v = (i < NN) ? deg[i] : 0;
  s[t] = v;
  __syncthreads();
  for (int off = 1; off < 256; off <<= 1) {
    int x = s[t];
    int y = (t >= off) ? s[t - off] : 0;
    __syncthreads();
    s[t] = x + y;
    __syncthreads();
  }
  if (i < NN) {
    int rs = bpre[blockIdx.x] + s[t] - v;
    rowstart[i] = rs;
    cursor[i] = rs;
  }
}

// CSR fill: single int2 (src, ea-bits) per edge -> one aligned 8B scatter store.
__global__ void fill_kernel(const int* __restrict__ ei, const float* __restrict__ ea,
                            int* __restrict__ cursor, int2* __restrict__ edges) {
  int e = blockIdx.x * 256 + threadIdx.x;
  if (e < NE) {
    int d = ei[NE + e];
    int pos = atomicAdd(&cursor[d], 1);
    edges[pos] = make_int2(ei[e], __float_as_int(ea[e]));
  }
}

// ---------------- fused GATv2 edge phase: wave per dst node (proven body) ----
__global__ __launch_bounds__(256) void gat_fused_kernel(
    const int* __restrict__ rowstart, const int2* __restrict__ edges,
    const unsigned short* __restrict__ xl, const unsigned short* __restrict__ xr,
    const float* __restrict__ we, const float* __restrict__ att,
    const float* __restrict__ bias, unsigned short* __restrict__ outb) {
  int node = (blockIdx.x * 256 + threadIdx.x) >> 6;
  int lane = threadIdx.x & 63;
  int r0 = __builtin_amdgcn_readfirstlane(rowstart[node]);
  int r1 = __builtin_amdgcn_readfirstlane(rowstart[node + 1]);
  const uint2* xl2 = (const uint2*)xl;
  uint2 rp = ((const uint2*)xr)[(size_t)node * 64 + lane];
  float4 r = make_float4(bflo(rp.x), bfhi(rp.x), bflo(rp.y), bfhi(rp.y));
  float4 wv = ((const float4*)we)[lane];
  float4 at = ((const float4*)att)[lane];
  const float LOG2E = 1.442695040888963f;
  at.x *= LOG2E; at.y *= LOG2E; at.z *= LOG2E; at.w *= LOG2E;
  float4 acc = make_float4(0.f, 0.f, 0.f, 0.f);
  float denom = 0.f;

  auto edge_step = [&](float eav, uint2 p) {
    float4 a = make_float4(bflo(p.x), bfhi(p.x), bflo(p.y), bfhi(p.y));
    float s0 = a.x + (r.x + eav * wv.x);
    float s1 = a.y + (r.y + eav * wv.y);
    float s2 = a.z + (r.z + eav * wv.z);
    float s3 = a.w + (r.w + eav * wv.w);
    s0 = fmaxf(s0, 0.2f * s0);
    s1 = fmaxf(s1, 0.2f * s1);
    s2 = fmaxf(s2, 0.2f * s2);
    s3 = fmaxf(s3, 0.2f * s3);
    float p4 = (s0 * at.x + s1 * at.y) + (s2 * at.z + s3 * at.w);
#pragma unroll
    for (int off = 8; off; off >>= 1) p4 += __shfl_xor(p4, off, 16);
    float ex = exp2f(p4);
    denom += ex;
    acc.x += ex * a.x; acc.y += ex * a.y; acc.z += ex * a.z; acc.w += ex * a.w;
  };

  int i = r0;
  for (; i + 4 <= r1; i += 4) {           // 4 gathers in flight (proven schedule)
    int2 e0 = edges[i];     int2 e1 = edges[i + 1];
    int2 e2 = edges[i + 2]; int2 e3 = edges[i + 3];
    uint2 p0 = xl2[(size_t)e0.x * 64 + lane];
    uint2 p1 = xl2[(size_t)e1.x * 64 + lane];
    uint2 p2 = xl2[(size_t)e2.x * 64 + lane];
    uint2 p3 = xl2[(size_t)e3.x * 64 + lane];
    edge_step(__int_as_float(e0.y), p0);
    edge_step(__int_as_float(e1.y), p1);
    edge_step(__int_as_float(e2.y), p2);
    edge_step(__int_as_float(e3.y), p3);
  }
  for (; i < r1; ++i) {
    int2 e = edges[i];
    edge_step(__int_as_float(e.y), xl2[(size_t)e.x * 64 + lane]);
  }

  float inv = 1.f / (denom + 1e-16f);
  float4 bv = ((const float4*)bias)[lane];
  float4 o;
  o.x = fmaxf(acc.x * inv + bv.x, 0.f);
  o.y = fmaxf(acc.y * inv + bv.y, 0.f);
  o.z = fmaxf(acc.z * inv + bv.z, 0.f);
  o.w = fmaxf(acc.w * inv + bv.w, 0.f);
  uint2 pk;
  pk.x = (unsigned)f2bf(o.x) | ((unsigned)f2bf(o.y) << 16);
  pk.y = (unsigned)f2bf(o.z) | ((unsigned)f2bf(o.w) << 16);
  ((uint2*)outb)[(size_t)node * 64 + lane] = pk;
}

// ---------------- pooling (bf16 input): block = 64 nodes, 4 rg x 64 lanes ----
__global__ __launch_bounds__(256) void pool_kernel(
    const unsigned short* __restrict__ h, const int* __restrict__ batch,
    float* __restrict__ pool) {
  int rg = threadIdx.x >> 6;
  int lane = threadIdx.x & 63;
  int n0 = blockIdx.x * 64;
  const uint2* h2 = (const uint2*)h;
  float4 acc = make_float4(0.f, 0.f, 0.f, 0.f);
  int cur = -1;
#pragma unroll 4
  for (int i = 0; i < 16; ++i) {
    int n = n0 + rg + 4 * i;
    if (n >= NN) break;
    int b = batch[n];
    if (b != cur) {
      if (cur >= 0) {
        float* p = &pool[cur * 256 + lane * 4];
        atomicAdd(p + 0, acc.x); atomicAdd(p + 1, acc.y);
        atomicAdd(p + 2, acc.z); atomicAdd(p + 3, acc.w);
      }
      cur = b;
      acc = make_float4(0.f, 0.f, 0.f, 0.f);
    }
    uint2 v = h2[(size_t)n * 64 + lane];
    acc.x += bflo(v.x); acc.y += bfhi(v.x);
    acc.z += bflo(v.y); acc.w += bfhi(v.y);
  }
  if (cur >= 0) {
    float* p = &pool[cur * 256 + lane * 4];
    atomicAdd(p + 0, acc.x); atomicAdd(p + 1, acc.y);
    atomicAdd(p + 2, acc.z); atomicAdd(p + 3, acc.w);
  }
}

// ---------------- final MLP: one block (128 thr) per graph ----------------
__global__ __launch_bounds__(128) void mlp_kernel(
    const float* __restrict__ pool, const int* __restrict__ bounds,
    const float* __restrict__ p1w, const float* __restrict__ p1b,
    const float* __restrict__ lng, const float* __restrict__ lnb,
    const float* __restrict__ p2w, const float* __restrict__ p2b,
    const float* __restrict__ hw, const float* __restrict__ hb,
    float* __restrict__ out) {
  __shared__ float sg[256];
  __shared__ float red[128];
  __shared__ float sz[128];
  __shared__ float s2[64];
  int b = blockIdx.x, tid = threadIdx.x;
  float cntf = (float)(bounds[b + 1] - bounds[b]);
  float invc = 1.f / fmaxf(cntf, 1.f);
  for (int i = tid; i < 256; i += 128) sg[i] = pool[b * 256 + i] * invc;
  __syncthreads();
  float z = p1b[tid];
  for (int k = 0; k < 256; ++k) z += sg[k] * p1w[k * 128 + tid];
  red[tid] = z; __syncthreads();
  for (int off = 64; off; off >>= 1) { if (tid < off) red[tid] += red[tid + off]; __syncthreads(); }
  float mu = red[0] * (1.f / 128.f);
  __syncthreads();
  float d = z - mu;
  red[tid] = d * d; __syncthreads();
  for (int off = 64; off; off >>= 1) { if (tid < off) red[tid] += red[tid + off]; __syncthreads(); }
  float var = red[0] * (1.f / 128.f);
  float zn = d * rsqrtf(var + 1e-5f) * lng[tid] + lnb[tid];
  sz[tid] = fmaxf(zn, 0.f);
  __syncthreads();
  if (tid < 64) {
    float a = p2b[tid];
    for (int k = 0; k < 128; ++k) a += sz[k] * p2w[k * 64 + tid];
    s2[tid] = fmaxf(a, 0.f);
  }
  __syncthreads();
  if (tid < 64) {
    float p = s2[tid] * hw[tid];
    for (int off = 32; off; off >>= 1) p += __shfl_down(p, off, 64);
    if (tid == 0) out[b] = p + hb[0];
  }
}

extern "C" void kernel_launch(void* const* d_in, const int* in_sizes, int n_in,
                              void* d_out, int out_size, void* d_ws, size_t ws_size,
                              hipStream_t stream) {
  const float* x      = (const float*)d_in[0];
  const int*   ei     = (const int*)d_in[1];
  const float* ea     = (const float*)d_in[2];
  const int*   batch  = (const int*)d_in[3];
  const float* enc_w  = (const float*)d_in[4];
  const float* enc_b  = (const float*)d_in[5];
  const float* g1_wl  = (const float*)d_in[6];
  const float* g1_bl  = (const float*)d_in[7];
  const float* g1_wr  = (const float*)d_in[8];
  const float* g1_we  = (const float*)d_in[9];
  const float* g1_att = (const float*)d_in[10];
  const float* g1_b   = (const float*)d_in[11];
  const float* g2_wl  = (const float*)d_in[12];
  const float* g2_bl  = (const float*)d_in[13];
  const float* g2_wr  = (const float*)d_in[14];
  const float* g2_we  = (const float*)d_in[15];
  const float* g2_att = (const float*)d_in[16];
  const float* g2_b   = (const float*)d_in[17];
  const float* p1_w   = (const float*)d_in[18];
  const float* p1_b   = (const float*)d_in[19];
  const float* ln_g   = (const float*)d_in[20];
  const float* ln_b   = (const float*)d_in[21];
  const float* p2_w   = (const float*)d_in[22];
  const float* p2_b   = (const float*)d_in[23];
  const float* head_w = (const float*)d_in[24];
  const float* head_b = (const float*)d_in[25];
  float* out = (float*)d_out;

  char* ws = (char*)d_ws;
  size_t off = 0;
  auto alloc = [&](size_t bytes) -> void* {
    void* p = ws + off;
    off = (off + bytes + 255) & ~(size_t)255;
    return p;
  };
  unsigned short* xl   = (unsigned short*)alloc((size_t)NN * HC * 2);
  unsigned short* xr   = (unsigned short*)alloc((size_t)NN * HC * 2);
  unsigned short* h0   = (unsigned short*)alloc((size_t)NN * 64 * 2);
  unsigned short* hb16 = (unsigned short*)alloc((size_t)NN * HC * 2);
  unsigned short* wt1  = (unsigned short*)alloc((size_t)512 * 64 * 2);
  unsigned short* wt2  = (unsigned short*)alloc((size_t)512 * 256 * 2);
  float* pool      = (float*)alloc((size_t)GG * HC * 4);
  int*   deg       = (int*)alloc((size_t)NN * 4);
  int*   rowstart  = (int*)alloc((size_t)(NN + 1) * 4);
  int*   cursor    = (int*)alloc((size_t)NN * 4);
  int*   bsum      = (int*)alloc((size_t)NB * 4);
  int*   bpre      = (int*)alloc((size_t)NB * 4);
  int2*  edges     = (int2*)alloc((size_t)NE * 8);
  int*   bounds    = (int*)alloc((size_t)(GG + 1) * 4);

  // setup: zero deg + zero pool + seg bounds (replaces 2 memsets + 1 kernel)
  setup_kernel<<<NB, 256, 0, stream>>>(batch, deg, pool, bounds);

  // encoder (bf16 out) + all weight prep in one launch
  encoder_kernel<<<NN * 64 / 256, 256, 0, stream>>>(x, enc_w, enc_b, h0);
  wconv_all_kernel<<<640, 256, 0, stream>>>(g1_wl, g1_wr, g2_wl, g2_wr, wt1, wt2);

  // CSR build: degree -> hierarchical scan -> fill
  degree_kernel<<<(NE + 255) / 256, 256, 0, stream>>>(ei, deg);
  blocksum_kernel<<<NB, 256, 0, stream>>>(deg, bsum);
  blockscan_kernel<<<1, 256, 0, stream>>>(bsum, bpre, rowstart);
  rowstart_kernel<<<NB, 256, 0, stream>>>(deg, bpre, rowstart, cursor);
  fill_kernel<<<(NE + 255) / 256, 256, 0, stream>>>(ei, ea, cursor, edges);

  dim3 mmg((NN + 127) / 128, 4);   // 391 x 4 blocks over the 512 concat cols

  // ---- GAT layer 1 (K=64): one matmul launch -> xl/xr, then edge phase ----
  matmul_mfma_kernel<64><<<mmg, 256, 0, stream>>>(h0, wt1, g1_bl, xl, xr, NN);
  gat_fused_kernel<<<NN / 4, 256, 0, stream>>>(rowstart, edges, xl, xr,
                                               g1_we, g1_att, g1_b, hb16);

  // ---- GAT layer 2 (K=256): matmul, then edge phase (bf16 out -> pooling) ----
  matmul_mfma_kernel<256><<<mmg, 256, 0, stream>>>(hb16, wt2, g2_bl, xl, xr, NN);
  gat_fused_kernel<<<NN / 4, 256, 0, stream>>>(rowstart, edges, xl, xr,
                                               g2_we, g2_att, g2_b, hb16);

  // ---- pooling (bf16 in) + MLP head ----
  pool_kernel<<<(NN + 63) / 64, 256, 0, stream>>>(hb16, batch, pool);
  mlp_kernel<<<GG, 128, 0, stream>>>(pool, bounds, p1_w, p1_b, ln_g, ln_b,
                                     p2_w, p2_b, head_w, head_b, out);
}

// Round 22
// 337.328 us; speedup vs baseline: 1.1667x; 1.0136x over previous
//
#include <hip/hip_runtime.h>
#include <hip/hip_bf16.h>
#include <math.h>

#define NN 50000     // nodes
#define NE 400000    // edges
#define HH 4         // heads
#define CC 64        // per-head dim
#define HC 256       // H*C
#define GG 64        // graphs
#define NB 196       // scan blocks: ceil(NN/256)
#define ENCB 12500   // encoder blocks
#define WCB 640      // wconv blocks

typedef short v8s __attribute__((ext_vector_type(8)));
typedef float f32x4 __attribute__((ext_vector_type(4)));

static __device__ inline unsigned short f2bf(float v) {
  __hip_bfloat16 b = __float2bfloat16(v);
  return *reinterpret_cast<unsigned short*>(&b);
}
// packed bf16 pair -> f32 (bf16 value = bit pattern << 16)
static __device__ inline float bflo(unsigned u) { return __uint_as_float(u << 16); }
static __device__ inline float bfhi(unsigned u) { return __uint_as_float(u & 0xffff0000u); }

// ---- head kernel: encoder + all 4 W preps + setup, region-dispatched ----
// bid <  ENCB               : encoder  h0 = relu(x @ enc_w + enc_b) -> bf16
// bid <  ENCB+WCB           : wconv    W[K,256] f32 -> Wt bf16 [256][K]
// bid <  ENCB+WCB+NB        : setup    zero deg, zero pool, seg bounds
__global__ __launch_bounds__(256) void head_kernel(
    const float* __restrict__ x, const float* __restrict__ enc_w,
    const float* __restrict__ enc_b, unsigned short* __restrict__ h0,
    const float* __restrict__ g1_wl, const float* __restrict__ g1_wr,
    const float* __restrict__ g2_wl, const float* __restrict__ g2_wr,
    unsigned short* __restrict__ wt1, unsigned short* __restrict__ wt2,
    const int* __restrict__ batch, int* __restrict__ deg,
    float* __restrict__ pool, int* __restrict__ bounds) {
  int bid = blockIdx.x, tid = threadIdx.x;
  if (bid < ENCB) {
    int idx = bid * 256 + tid;
    int node = idx >> 6, col = idx & 63;
    const float* xr = x + node * 8;
    float acc = enc_b[col];
#pragma unroll
    for (int k = 0; k < 8; ++k) acc += xr[k] * enc_w[k * 64 + col];
    h0[idx] = f2bf(fmaxf(acc, 0.f));
  } else if (bid < ENCB + WCB) {
    int idx = (bid - ENCB) * 256 + tid;
    const float* W; unsigned short* Wt; int K; int base;
    if (idx < 16384)        { W = g1_wl; Wt = wt1;                     K = 64;  base = idx; }
    else if (idx < 32768)   { W = g1_wr; Wt = wt1 + (size_t)256 * 64;  K = 64;  base = idx - 16384; }
    else if (idx < 98304)   { W = g2_wl; Wt = wt2;                     K = 256; base = idx - 32768; }
    else if (idx < 163840)  { W = g2_wr; Wt = wt2 + (size_t)256 * 256; K = 256; base = idx - 98304; }
    else return;
    int k = base >> 8, n = base & 255;
    Wt[n * K + k] = f2bf(W[base]);
  } else {
    int sb = bid - ENCB - WCB;           // 0..NB-1
    int i = sb * 256 + tid;
    if (i < NN) deg[i] = 0;
    if (sb < GG) pool[sb * 256 + tid] = 0.f;
    if (sb == NB - 1 && tid <= GG) {
      int g = tid, lo = 0, hi = NN;
      while (lo < hi) {
        int mid = (lo + hi) >> 1;
        if (batch[mid] < g) lo = mid + 1; else hi = mid;
      }
      bounds[g] = lo;
    }
  }
}

// ------- MFMA matmul: {xl,xr}(bf16)[M,256] = A(bf16) @ [Wl;Wr] (bias on xl) -------
// Wcat = [512][K] k-contiguous rows. Block 128 rows x 128 cols, blockIdx.y 0..3.
// Epilogue routes C through LDS -> 256B-coalesced uint4 row stores.
template <int K>
__global__ __launch_bounds__(256) void matmul_mfma_kernel(
    const unsigned short* __restrict__ A, const unsigned short* __restrict__ Wt,
    const float* __restrict__ bias,
    unsigned short* __restrict__ outL, unsigned short* __restrict__ outR, int M) {
  constexpr int AP = 40;                 // LDS k-stride (shorts): 80B, 16B-aligned
  __shared__ unsigned short a_lds[128 * AP];   // 10240 B (also reused as C stage)
  __shared__ unsigned short b_lds[128 * AP];
  const int tid = threadIdx.x;
  const int wave = tid >> 6;
  const int lane = tid & 63;
  const int quad = lane >> 4;
  const int lrow = lane & 15;
  const int wr = (wave & 1) * 64;
  const int wc = (wave >> 1) * 64;
  const int r0 = blockIdx.x * 128;
  const int n0 = blockIdx.y * 128;       // 0..384 over the 512 concat cols

  f32x4 acc[4][4];
#pragma unroll
  for (int i = 0; i < 4; ++i)
#pragma unroll
    for (int j = 0; j < 4; ++j) acc[i][j] = (f32x4){0.f, 0.f, 0.f, 0.f};

  const int srow = tid >> 1;
  const int shalf = tid & 1;
  int agrow = r0 + srow; if (agrow >= M) agrow = M - 1;   // clamp; stores guarded
  const int bgrow = n0 + srow;

  for (int k0 = 0; k0 < K; k0 += 32) {
    {
      const float4* sa = (const float4*)&A[(size_t)agrow * K + k0 + shalf * 16];
      const float4* sb = (const float4*)&Wt[(size_t)bgrow * K + k0 + shalf * 16];
      float4 va0 = sa[0], va1 = sa[1];
      float4 vb0 = sb[0], vb1 = sb[1];
      *(float4*)&a_lds[srow * AP + shalf * 16]     = va0;
      *(float4*)&a_lds[srow * AP + shalf * 16 + 8] = va1;
      *(float4*)&b_lds[srow * AP + shalf * 16]     = vb0;
      *(float4*)&b_lds[srow * AP + shalf * 16 + 8] = vb1;
    }
    __syncthreads();

    v8s af[4], bf[4];
#pragma unroll
    for (int rt = 0; rt < 4; ++rt)
      af[rt] = *(const v8s*)&a_lds[(wr + rt * 16 + lrow) * AP + quad * 8];
#pragma unroll
    for (int ct = 0; ct < 4; ++ct)
      bf[ct] = *(const v8s*)&b_lds[(wc + ct * 16 + lrow) * AP + quad * 8];
#pragma unroll
    for (int rt = 0; rt < 4; ++rt)
#pragma unroll
      for (int ct = 0; ct < 4; ++ct)
        acc[rt][ct] = __builtin_amdgcn_mfma_f32_16x16x32_bf16(af[rt], bf[ct], acc[rt][ct], 0, 0, 0);
    __syncthreads();
  }

  const bool isL = (n0 < 256);
  unsigned short* outp = isL ? outL : outR;
  const int cbase = isL ? n0 : (n0 - 256);
  constexpr int SP = 136;                // stage row stride (272B: 16B-mult, bank-spread)
  unsigned short* stage = a_lds;         // 32*136*2 = 8704B <= 10240B

#pragma unroll
  for (int rt = 0; rt < 4; ++rt) {
    __syncthreads();                     // stage free (prev rt reads / k-loop done)
#pragma unroll
    for (int ct = 0; ct < 4; ++ct) {
      int col = wc + ct * 16 + lrow;     // 0..127 within block
      float b = isL ? bias[cbase + col] : 0.f;
#pragma unroll
      for (int r = 0; r < 4; ++r) {
        int sr = (wave & 1) * 16 + quad * 4 + r;   // 0..31
        stage[sr * SP + col] = f2bf(acc[rt][ct][r] + b);
      }
    }
    __syncthreads();
    int sr = tid >> 3;                   // 0..31
    int c0 = (tid & 7) * 16;             // shorts; 8 threads cover 128 cols
    int grow = r0 + (sr >> 4) * 64 + rt * 16 + (sr & 15);
    if (grow < M) {
      uint4 v0 = *(const uint4*)&stage[sr * SP + c0];
      uint4 v1 = *(const uint4*)&stage[sr * SP + c0 + 8];
      *(uint4*)&outp[(size_t)grow * 256 + cbase + c0] = v0;
      *(uint4*)&outp[(size_t)grow * 256 + cbase + c0 + 8] = v1;
    }
  }
}

// ---------------- CSR build ----------------
__global__ void degree_kernel(const int* __restrict__ ei, int* __restrict__ deg) {
  int e = blockIdx.x * 256 + threadIdx.x;
  if (e < NE) atomicAdd(&deg[ei[NE + e]], 1);
}

__global__ __launch_bounds__(256) void blocksum_kernel(
    const int* __restrict__ deg, int* __restrict__ bsum) {
  int t = threadIdx.x;
  int i = blockIdx.x * 256 + t;
  int v = (i < NN) ? deg[i] : 0;
#pragma unroll
  for (int off = 32; off; off >>= 1) v += __shfl_down(v, off, 64);
  __shared__ int ws[4];
  if ((t & 63) == 0) ws[t >> 6] = v;
  __syncthreads();
  if (t == 0) bsum[blockIdx.x] = ws[0] + ws[1] + ws[2] + ws[3];
}

__global__ __launch_bounds__(256) void blockscan_kernel(
    const int* __restrict__ bsum, int* __restrict__ bpre, int* __restrict__ rowstart) {
  __shared__ int s[256];
  int t = threadIdx.x;
  int v = (t < NB) ? bsum[t] : 0;
  s[t] = v;
  __syncthreads();
  for (int off = 1; off < 256; off <<= 1) {
    int x = s[t];
    int y = (t >= off) ? s[t - off] : 0;
    __syncthreads();
    s[t] = x + y;
    __syncthreads();
  }
  if (t < NB) bpre[t] = s[t] - v;
  if (t == 255) rowstart[NN] = s[255];
}

__global__ __launch_bounds__(256) void rowstart_kernel(
    const int* __restrict__ deg, const int* __restrict__ bpre,
    int* __restrict__ rowstart, int* __restrict__ cursor) {
  __shared__ int s[256];
  int t = threadIdx.x;
  int i = blockIdx.x * 256 + t;
  int v = (i < NN) ? deg[i] : 0;
  s[t] = v;
  __syncthreads();
  for (int off = 1; off < 256; off <<= 1) {
    int x = s[t];
    int y = (t >= off) ? s[t - off] : 0;
    __syncthreads();
    s[t] = x + y;
    __syncthreads();
  }
  if (i < NN) {
    int rs = bpre[blockIdx.x] + s[t] - v;
    rowstart[i] = rs;
    cursor[i] = rs;
  }
}

// CSR fill: int2 (src BYTE OFFSET = src*512, ea-bits) -> one aligned 8B store.
// Premultiplied offset kills the per-gather mad64 in gat_fused.
__global__ void fill_kernel(const int* __restrict__ ei, const float* __restrict__ ea,
                            int* __restrict__ cursor, int2* __restrict__ edges) {
  int e = blockIdx.x * 256 + threadIdx.x;
  if (e < NE) {
    int d = ei[NE + e];
    int pos = atomicAdd(&cursor[d], 1);
    edges[pos] = make_int2(ei[e] << 9, __float_as_int(ea[e]));
  }
}

// ---------------- fused GATv2 edge phase: wave per dst node (proven body) ----
// edges[].x is a premultiplied byte offset; lane*8 folded into base pointer.
__global__ __launch_bounds__(256) void gat_fused_kernel(
    const int* __restrict__ rowstart, const int2* __restrict__ edges,
    const unsigned short* __restrict__ xl, const unsigned short* __restrict__ xr,
    const float* __restrict__ we, const float* __restrict__ att,
    const float* __restrict__ bias, unsigned short* __restrict__ outb) {
  int node = (blockIdx.x * 256 + threadIdx.x) >> 6;
  int lane = threadIdx.x & 63;
  int r0 = __builtin_amdgcn_readfirstlane(rowstart[node]);
  int r1 = __builtin_amdgcn_readfirstlane(rowstart[node + 1]);
  const char* xlp = (const char*)xl + lane * 8;   // per-thread gather base
  uint2 rp = ((const uint2*)xr)[(size_t)node * 64 + lane];
  float4 r = make_float4(bflo(rp.x), bfhi(rp.x), bflo(rp.y), bfhi(rp.y));
  float4 wv = ((const float4*)we)[lane];
  float4 at = ((const float4*)att)[lane];
  const float LOG2E = 1.442695040888963f;
  at.x *= LOG2E; at.y *= LOG2E; at.z *= LOG2E; at.w *= LOG2E;
  float4 acc = make_float4(0.f, 0.f, 0.f, 0.f);
  float denom = 0.f;

  auto edge_step = [&](float eav, uint2 p) {
    float4 a = make_float4(bflo(p.x), bfhi(p.x), bflo(p.y), bfhi(p.y));
    float s0 = a.x + (r.x + eav * wv.x);
    float s1 = a.y + (r.y + eav * wv.y);
    float s2 = a.z + (r.z + eav * wv.z);
    float s3 = a.w + (r.w + eav * wv.w);
    s0 = fmaxf(s0, 0.2f * s0);
    s1 = fmaxf(s1, 0.2f * s1);
    s2 = fmaxf(s2, 0.2f * s2);
    s3 = fmaxf(s3, 0.2f * s3);
    float p4 = (s0 * at.x + s1 * at.y) + (s2 * at.z + s3 * at.w);
#pragma unroll
    for (int off = 8; off; off >>= 1) p4 += __shfl_xor(p4, off, 16);
    float ex = exp2f(p4);
    denom += ex;
    acc.x += ex * a.x; acc.y += ex * a.y; acc.z += ex * a.z; acc.w += ex * a.w;
  };

  int i = r0;
  for (; i + 4 <= r1; i += 4) {           // 4 gathers in flight (proven schedule)
    int2 e0 = edges[i];     int2 e1 = edges[i + 1];
    int2 e2 = edges[i + 2]; int2 e3 = edges[i + 3];
    uint2 p0 = *(const uint2*)(xlp + (unsigned)e0.x);
    uint2 p1 = *(const uint2*)(xlp + (unsigned)e1.x);
    uint2 p2 = *(const uint2*)(xlp + (unsigned)e2.x);
    uint2 p3 = *(const uint2*)(xlp + (unsigned)e3.x);
    edge_step(__int_as_float(e0.y), p0);
    edge_step(__int_as_float(e1.y), p1);
    edge_step(__int_as_float(e2.y), p2);
    edge_step(__int_as_float(e3.y), p3);
  }
  for (; i < r1; ++i) {
    int2 e = edges[i];
    edge_step(__int_as_float(e.y), *(const uint2*)(xlp + (unsigned)e.x));
  }

  float inv = 1.f / (denom + 1e-16f);
  float4 bv = ((const float4*)bias)[lane];
  float4 o;
  o.x = fmaxf(acc.x * inv + bv.x, 0.f);
  o.y = fmaxf(acc.y * inv + bv.y, 0.f);
  o.z = fmaxf(acc.z * inv + bv.z, 0.f);
  o.w = fmaxf(acc.w * inv + bv.w, 0.f);
  uint2 pk;
  pk.x = (unsigned)f2bf(o.x) | ((unsigned)f2bf(o.y) << 16);
  pk.y = (unsigned)f2bf(o.z) | ((unsigned)f2bf(o.w) << 16);
  ((uint2*)outb)[(size_t)node * 64 + lane] = pk;
}

// ---------------- pooling (bf16 input): block = 64 nodes, 4 rg x 64 lanes ----
__global__ __launch_bounds__(256) void pool_kernel(
    const unsigned short* __restrict__ h, const int* __restrict__ batch,
    float* __restrict__ pool) {
  int rg = threadIdx.x >> 6;
  int lane = threadIdx.x & 63;
  int n0 = blockIdx.x * 64;
  const uint2* h2 = (const uint2*)h;
  float4 acc = make_float4(0.f, 0.f, 0.f, 0.f);
  int cur = -1;
#pragma unroll 4
  for (int i = 0; i < 16; ++i) {
    int n = n0 + rg + 4 * i;
    if (n >= NN) break;
    int b = batch[n];
    if (b != cur) {
      if (cur >= 0) {
        float* p = &pool[cur * 256 + lane * 4];
        atomicAdd(p + 0, acc.x); atomicAdd(p + 1, acc.y);
        atomicAdd(p + 2, acc.z); atomicAdd(p + 3, acc.w);
      }
      cur = b;
      acc = make_float4(0.f, 0.f, 0.f, 0.f);
    }
    uint2 v = h2[(size_t)n * 64 + lane];
    acc.x += bflo(v.x); acc.y += bfhi(v.x);
    acc.z += bflo(v.y); acc.w += bfhi(v.y);
  }
  if (cur >= 0) {
    float* p = &pool[cur * 256 + lane * 4];
    atomicAdd(p + 0, acc.x); atomicAdd(p + 1, acc.y);
    atomicAdd(p + 2, acc.z); atomicAdd(p + 3, acc.w);
  }
}

// ---------------- final MLP: one block (128 thr) per graph ----------------
__global__ __launch_bounds__(128) void mlp_kernel(
    const float* __restrict__ pool, const int* __restrict__ bounds,
    const float* __restrict__ p1w, const float* __restrict__ p1b,
    const float* __restrict__ lng, const float* __restrict__ lnb,
    const float* __restrict__ p2w, const float* __restrict__ p2b,
    const float* __restrict__ hw, const float* __restrict__ hb,
    float* __restrict__ out) {
  __shared__ float sg[256];
  __shared__ float red[128];
  __shared__ float sz[128];
  __shared__ float s2[64];
  int b = blockIdx.x, tid = threadIdx.x;
  float cntf = (float)(bounds[b + 1] - bounds[b]);
  float invc = 1.f / fmaxf(cntf, 1.f);
  for (int i = tid; i < 256; i += 128) sg[i] = pool[b * 256 + i] * invc;
  __syncthreads();
  float z = p1b[tid];
  for (int k = 0; k < 256; ++k) z += sg[k] * p1w[k * 128 + tid];
  red[tid] = z; __syncthreads();
  for (int off = 64; off; off >>= 1) { if (tid < off) red[tid] += red[tid + off]; __syncthreads(); }
  float mu = red[0] * (1.f / 128.f);
  __syncthreads();
  float d = z - mu;
  red[tid] = d * d; __syncthreads();
  for (int off = 64; off; off >>= 1) { if (tid < off) red[tid] += red[tid + off]; __syncthreads(); }
  float var = red[0] * (1.f / 128.f);
  float zn = d * rsqrtf(var + 1e-5f) * lng[tid] + lnb[tid];
  sz[tid] = fmaxf(zn, 0.f);
  __syncthreads();
  if (tid < 64) {
    float a = p2b[tid];
    for (int k = 0; k < 128; ++k) a += sz[k] * p2w[k * 64 + tid];
    s2[tid] = fmaxf(a, 0.f);
  }
  __syncthreads();
  if (tid < 64) {
    float p = s2[tid] * hw[tid];
    for (int off = 32; off; off >>= 1) p += __shfl_down(p, off, 64);
    if (tid == 0) out[b] = p + hb[0];
  }
}

extern "C" void kernel_launch(void* const* d_in, const int* in_sizes, int n_in,
                              void* d_out, int out_size, void* d_ws, size_t ws_size,
                              hipStream_t stream) {
  const float* x      = (const float*)d_in[0];
  const int*   ei     = (const int*)d_in[1];
  const float* ea     = (const float*)d_in[2];
  const int*   batch  = (const int*)d_in[3];
  const float* enc_w  = (const float*)d_in[4];
  const float* enc_b  = (const float*)d_in[5];
  const float* g1_wl  = (const float*)d_in[6];
  const float* g1_bl  = (const float*)d_in[7];
  const float* g1_wr  = (const float*)d_in[8];
  const float* g1_we  = (const float*)d_in[9];
  const float* g1_att = (const float*)d_in[10];
  const float* g1_b   = (const float*)d_in[11];
  const float* g2_wl  = (const float*)d_in[12];
  const float* g2_bl  = (const float*)d_in[13];
  const float* g2_wr  = (const float*)d_in[14];
  const float* g2_we  = (const float*)d_in[15];
  const float* g2_att = (const float*)d_in[16];
  const float* g2_b   = (const float*)d_in[17];
  const float* p1_w   = (const float*)d_in[18];
  const float* p1_b   = (const float*)d_in[19];
  const float* ln_g   = (const float*)d_in[20];
  const float* ln_b   = (const float*)d_in[21];
  const float* p2_w   = (const float*)d_in[22];
  const float* p2_b   = (const float*)d_in[23];
  const float* head_w = (const float*)d_in[24];
  const float* head_b = (const float*)d_in[25];
  float* out = (float*)d_out;

  char* ws = (char*)d_ws;
  size_t off = 0;
  auto alloc = [&](size_t bytes) -> void* {
    void* p = ws + off;
    off = (off + bytes + 255) & ~(size_t)255;
    return p;
  };
  unsigned short* xl   = (unsigned short*)alloc((size_t)NN * HC * 2);
  unsigned short* xr   = (unsigned short*)alloc((size_t)NN * HC * 2);
  unsigned short* h0   = (unsigned short*)alloc((size_t)NN * 64 * 2);
  unsigned short* hb16 = (unsigned short*)alloc((size_t)NN * HC * 2);
  unsigned short* wt1  = (unsigned short*)alloc((size_t)512 * 64 * 2);
  unsigned short* wt2  = (unsigned short*)alloc((size_t)512 * 256 * 2);
  float* pool      = (float*)alloc((size_t)GG * HC * 4);
  int*   deg       = (int*)alloc((size_t)NN * 4);
  int*   rowstart  = (int*)alloc((size_t)(NN + 1) * 4);
  int*   cursor    = (int*)alloc((size_t)NN * 4);
  int*   bsum      = (int*)alloc((size_t)NB * 4);
  int*   bpre      = (int*)alloc((size_t)NB * 4);
  int2*  edges     = (int2*)alloc((size_t)NE * 8);
  int*   bounds    = (int*)alloc((size_t)(GG + 1) * 4);

  // encoder + weight prep + setup (zero deg/pool, seg bounds) in ONE launch
  head_kernel<<<ENCB + WCB + NB, 256, 0, stream>>>(
      x, enc_w, enc_b, h0, g1_wl, g1_wr, g2_wl, g2_wr, wt1, wt2,
      batch, deg, pool, bounds);

  // CSR build: degree -> hierarchical scan -> fill
  degree_kernel<<<(NE + 255) / 256, 256, 0, stream>>>(ei, deg);
  blocksum_kernel<<<NB, 256, 0, stream>>>(deg, bsum);
  blockscan_kernel<<<1, 256, 0, stream>>>(bsum, bpre, rowstart);
  rowstart_kernel<<<NB, 256, 0, stream>>>(deg, bpre, rowstart, cursor);
  fill_kernel<<<(NE + 255) / 256, 256, 0, stream>>>(ei, ea, cursor, edges);

  dim3 mmg((NN + 127) / 128, 4);   // 391 x 4 blocks over the 512 concat cols

  // ---- GAT layer 1 (K=64): one matmul launch -> xl/xr, then edge phase ----
  matmul_mfma_kernel<64><<<mmg, 256, 0, stream>>>(h0, wt1, g1_bl, xl, xr, NN);
  gat_fused_kernel<<<NN / 4, 256, 0, stream>>>(rowstart, edges, xl, xr,
                                               g1_we, g1_att, g1_b, hb16);

  // ---- GAT layer 2 (K=256): matmul, then edge phase (bf16 out -> pooling) ----
  matmul_mfma_kernel<256><<<mmg, 256, 0, stream>>>(hb16, wt2, g2_bl, xl, xr, NN);
  gat_fused_kernel<<<NN / 4, 256, 0, stream>>>(rowstart, edges, xl, xr,
                                               g2_we, g2_att, g2_b, hb16);

  // ---- pooling (bf16 in) + MLP head ----
  pool_kernel<<<(NN + 63) / 64, 256, 0, stream>>>(hb16, batch, pool);
  mlp_kernel<<<GG, 128, 0, stream>>>(pool, bounds, p1_w, p1_b, ln_g, ln_b,
                                     p2_w, p2_b, head_w, head_b, out);
}